// Round 2
// baseline (8337.549 us; speedup 1.0000x reference)
//
#include <hip/hip_runtime.h>
#include <hip/hip_bf16.h>

// Mamba2 mixer — bf16 intermediates, fp32 compute. Workspace ~195 MiB.
// B=2 S=2048 HID=2048 INTER=4096 NH=64 HD=64 NG=8 SS=128 CK=4 CH=256 NC=8
// PROJ=10304 CONV_DIM=6144

#define S_LEN 2048
#define HIDDEN 2048
#define INTER 4096
#define NH 64
#define HD 64
#define NG 8
#define SSZ 128
#define CONV_DIM 6144
#define PROJ_DIM 10304
#define NC 8
#define CHK 256
#define ROWS 4096          // B*S
#define DT_OFF 10240       // INTER + CONV_DIM
#define B_OFF 4096         // B section inside conv block
#define C_OFF 5120         // C section inside conv block

typedef __hip_bfloat16 bf16;

__device__ __forceinline__ float siluf(float x) { return x / (1.f + __expf(-x)); }
__device__ __forceinline__ float ldf(const float* p) { return *p; }
__device__ __forceinline__ float ldf(const bf16* p) { return __bfloat162float(*p); }
__device__ __forceinline__ void st4(float* p, float4 v) { *reinterpret_cast<float4*>(p) = v; }
__device__ __forceinline__ void st4(bf16* p, float4 v) {
  union { ushort4 u; bf16 h[4]; } pk;
  pk.h[0] = __float2bfloat16(v.x); pk.h[1] = __float2bfloat16(v.y);
  pk.h[2] = __float2bfloat16(v.z); pk.h[3] = __float2bfloat16(v.w);
  *reinterpret_cast<ushort4*>(p) = pk.u;
}

// ---------------- GEMM: C[M,N] = A[M,K] @ B[K,N], fp32 accumulate ----------------
// BM=BN=64, BK=16, 256 threads, 4x4 micro-tile.
template <typename TA, typename TC>
__global__ __launch_bounds__(256) void gemm_t(const TA* __restrict__ A,
                                              const float* __restrict__ B,
                                              TC* __restrict__ C,
                                              int M, int N, int K) {
  __shared__ __align__(16) float As[16][68];
  __shared__ __align__(16) float Bs[16][68];
  const int tid = threadIdx.x;
  const int m0 = blockIdx.y * 64;
  const int n0 = blockIdx.x * 64;
  const int tr = tid >> 4;
  const int tc = tid & 15;
  float acc[4][4] = {};
  for (int kt = 0; kt < K; kt += 16) {
#pragma unroll
    for (int i = 0; i < 4; i++) {
      int idx = tid + i * 256;
      int r = idx >> 4;      // 0..63
      int c = idx & 15;      // 0..15
      As[c][r] = ldf(&A[(size_t)(m0 + r) * K + kt + c]);
    }
#pragma unroll
    for (int i = 0; i < 4; i++) {
      int idx = tid + i * 256;
      int r = idx >> 6;      // 0..15
      int c = idx & 63;      // 0..63
      Bs[r][c] = B[(size_t)(kt + r) * N + n0 + c];
    }
    __syncthreads();
#pragma unroll
    for (int k = 0; k < 16; k++) {
      const float4 av = *reinterpret_cast<const float4*>(&As[k][tr * 4]);
      const float4 bv = *reinterpret_cast<const float4*>(&Bs[k][tc * 4]);
      acc[0][0] += av.x * bv.x; acc[0][1] += av.x * bv.y; acc[0][2] += av.x * bv.z; acc[0][3] += av.x * bv.w;
      acc[1][0] += av.y * bv.x; acc[1][1] += av.y * bv.y; acc[1][2] += av.y * bv.z; acc[1][3] += av.y * bv.w;
      acc[2][0] += av.z * bv.x; acc[2][1] += av.z * bv.y; acc[2][2] += av.z * bv.z; acc[2][3] += av.z * bv.w;
      acc[3][0] += av.w * bv.x; acc[3][1] += av.w * bv.y; acc[3][2] += av.w * bv.z; acc[3][3] += av.w * bv.w;
    }
    __syncthreads();
  }
#pragma unroll
  for (int i = 0; i < 4; i++) {
    float4 v = make_float4(acc[i][0], acc[i][1], acc[i][2], acc[i][3]);
    st4(&C[(size_t)(m0 + tr * 4 + i) * N + n0 + tc * 4], v);
  }
}

// ---------------- depthwise conv (SAME, k=4, pad_lo=1) + SiLU ----------------
__global__ __launch_bounds__(256) void conv_silu_k(const bf16* __restrict__ proj,
                                                   const float* __restrict__ cw,
                                                   const float* __restrict__ cb,
                                                   bf16* __restrict__ convo) {
  int idx = blockIdx.x * 256 + threadIdx.x;  // < ROWS*CONV_DIM
  int c = idx % CONV_DIM;
  int row = idx / CONV_DIM;
  int t = row & (S_LEN - 1);
  int b = row >> 11;
  float acc = cb[c];
#pragma unroll
  for (int w = 0; w < 4; w++) {
    int tt = t + w - 1;
    if (tt >= 0 && tt < S_LEN)
      acc += cw[w * CONV_DIM + c] * ldf(&proj[(size_t)(b * S_LEN + tt) * PROJ_DIM + INTER + c]);
  }
  convo[idx] = __float2bfloat16(siluf(acc));
}

// ---------------- dt = softplus(dt_raw + dt_bias) ----------------
__global__ __launch_bounds__(256) void dt_k(const bf16* __restrict__ proj,
                                            const float* __restrict__ dtb,
                                            float* __restrict__ dtp) {
  int idx = blockIdx.x * 256 + threadIdx.x;  // < ROWS*NH
  int h = idx & 63;
  int row = idx >> 6;
  float x = ldf(&proj[(size_t)row * PROJ_DIM + DT_OFF + h]) + dtb[h];
  dtp[idx] = (x > 20.f) ? x : log1pf(__expf(x));
}

// ---------------- per-chunk cumsum of A[h]*dt ----------------
__global__ __launch_bounds__(256) void acum_k(const float* __restrict__ dtp,
                                              const float* __restrict__ alog,
                                              float* __restrict__ acum) {
  __shared__ float buf[2][CHK];
  int blk = blockIdx.x;
  int c = blk & 7;
  int h = (blk >> 3) & 63;
  int b = blk >> 9;
  int tid = threadIdx.x;
  int row0 = b * S_LEN + c * CHK;
  float a = -__expf(alog[h]);
  buf[0][tid] = a * dtp[(size_t)(row0 + tid) * NH + h];
  __syncthreads();
  int cur = 0;
#pragma unroll
  for (int off = 1; off < 256; off <<= 1) {
    float nv = buf[cur][tid];
    if (tid >= off) nv += buf[cur][tid - off];
    buf[cur ^ 1][tid] = nv;
    cur ^= 1;
    __syncthreads();
  }
  acum[(size_t)blk * CHK + tid] = buf[cur][tid];
}

// ---------------- per-chunk states ----------------
__global__ __launch_bounds__(256) void chunk_states_k(const bf16* __restrict__ convo,
                                                      const float* __restrict__ dtp,
                                                      const float* __restrict__ acum,
                                                      float* __restrict__ cs) {
  __shared__ float sAc[CHK];
  __shared__ float sDt[CHK];
  __shared__ __align__(16) float hst[64][68];
  __shared__ __align__(16) float Bd[64][132];
  int blk = blockIdx.x;
  int h = blk & 63;
  int bc = blk >> 6;
  int c = bc & 7;
  int b = bc >> 3;
  int g = h >> 3;
  int tid = threadIdx.x;
  int row0 = b * S_LEN + c * CHK;
  sAc[tid] = acum[((size_t)((b * NH + h) * NC + c)) * CHK + tid];
  sDt[tid] = dtp[(size_t)(row0 + tid) * NH + h];
  __syncthreads();
  float alast = sAc[CHK - 1];
  int tx = tid & 31, ty = tid >> 5;
  float acc[8][4] = {};
  for (int ts = 0; ts < CHK; ts += 64) {
#pragma unroll
    for (int i = 0; i < 16; i++) {
      int idx = tid + i * 256;
      int t = idx >> 6, p = idx & 63;
      hst[t][p] = ldf(&convo[(size_t)(row0 + ts + t) * CONV_DIM + h * HD + p]) * sDt[ts + t];
    }
#pragma unroll
    for (int i = 0; i < 32; i++) {
      int idx = tid + i * 256;
      int t = idx >> 7, n = idx & 127;
      Bd[t][n] = ldf(&convo[(size_t)(row0 + ts + t) * CONV_DIM + B_OFF + g * SSZ + n]) *
                 __expf(alast - sAc[ts + t]);
    }
    __syncthreads();
#pragma unroll
    for (int t = 0; t < 64; t++) {
      float4 bv = *reinterpret_cast<const float4*>(&Bd[t][tx * 4]);
#pragma unroll
      for (int k = 0; k < 8; k++) {
        float hv = hst[t][ty + 8 * k];
        acc[k][0] += hv * bv.x; acc[k][1] += hv * bv.y;
        acc[k][2] += hv * bv.z; acc[k][3] += hv * bv.w;
      }
    }
    __syncthreads();
  }
  size_t base = (size_t)blk * HD * SSZ;  // [b][c][h][p][n]
#pragma unroll
  for (int k = 0; k < 8; k++) {
    float4 v = make_float4(acc[k][0], acc[k][1], acc[k][2], acc[k][3]);
    *reinterpret_cast<float4*>(&cs[base + (size_t)(ty + 8 * k) * SSZ + tx * 4]) = v;
  }
}

// ---------------- inter-chunk recurrence (in-place) ----------------
__global__ __launch_bounds__(256) void chunk_rec_k(const float* __restrict__ acum,
                                                   float* __restrict__ cs) {
  int idx = blockIdx.x * 256 + threadIdx.x;  // < 2*64*64*128
  int n = idx & 127;
  int p = (idx >> 7) & 63;
  int h = (idx >> 13) & 63;
  int b = idx >> 19;
  float run = 0.f;
#pragma unroll
  for (int c = 0; c < NC; c++) {
    size_t off = ((size_t)(((b * NC + c) * NH + h) * HD + p)) * SSZ + n;
    float csv = cs[off];
    float al = acum[((size_t)((b * NH + h) * NC + c)) * CHK + (CHK - 1)];
    cs[off] = run;
    run = run * __expf(al) + csv;
  }
}

// ---------------- chunk output: Y_diag + Y_off + D*hs -> yb ----------------
__global__ __launch_bounds__(256) void chunk_out_k(const bf16* __restrict__ convo,
                                                   const float* __restrict__ dtp,
                                                   const float* __restrict__ acum,
                                                   const float* __restrict__ cs,
                                                   const float* __restrict__ Dp,
                                                   bf16* __restrict__ yb) {
  __shared__ float sAc[CHK];
  __shared__ float sDt[CHK];
  __shared__ __align__(16) float Ct[32][132];
  __shared__ __align__(16) float Bst[32][132];
  __shared__ float hst[32][68];
  __shared__ float Wt[32][68];
  int blk = blockIdx.x;
  int lt = blk & 7;
  int rest = blk >> 3;
  int h = rest & 63;
  int bc = rest >> 6;
  int c = bc & 7;
  int b = bc >> 3;
  int g = h >> 3;
  int tid = threadIdx.x;
  int row0 = b * S_LEN + c * CHK;
  int L0 = lt * 32;
  sAc[tid] = acum[((size_t)((b * NH + h) * NC + c)) * CHK + tid];
  sDt[tid] = dtp[(size_t)(row0 + tid) * NH + h];
#pragma unroll
  for (int i = 0; i < 16; i++) {
    int idx = tid + i * 256;
    int r = idx >> 7, n = idx & 127;
    Ct[r][n] = ldf(&convo[(size_t)(row0 + L0 + r) * CONV_DIM + C_OFF + g * SSZ + n]);
  }
  __syncthreads();
  const int l0 = tid & 15;
  const int s0 = tid >> 4;
  const int p = tid & 63;
  const int rg = tid >> 6;
  float acc[8] = {};
  for (int st = 0; st <= lt; st++) {
    int sbase = st * 32;
#pragma unroll
    for (int i = 0; i < 16; i++) {
      int idx = tid + i * 256;
      int r = idx >> 7, n = idx & 127;
      Bst[r][n] = ldf(&convo[(size_t)(row0 + sbase + r) * CONV_DIM + B_OFF + g * SSZ + n]);
    }
#pragma unroll
    for (int i = 0; i < 8; i++) {
      int idx = tid + i * 256;
      int t = idx >> 6, pp = idx & 63;
      hst[t][pp] = ldf(&convo[(size_t)(row0 + sbase + t) * CONV_DIM + h * HD + pp]) * sDt[sbase + t];
    }
    __syncthreads();
    float d00 = 0.f, d01 = 0.f, d10 = 0.f, d11 = 0.f;
#pragma unroll
    for (int n4 = 0; n4 < 32; n4++) {
      float4 c0 = *reinterpret_cast<const float4*>(&Ct[l0][n4 * 4]);
      float4 c1 = *reinterpret_cast<const float4*>(&Ct[l0 + 16][n4 * 4]);
      float4 b0 = *reinterpret_cast<const float4*>(&Bst[s0][n4 * 4]);
      float4 b1 = *reinterpret_cast<const float4*>(&Bst[s0 + 16][n4 * 4]);
      d00 += c0.x * b0.x + c0.y * b0.y + c0.z * b0.z + c0.w * b0.w;
      d01 += c0.x * b1.x + c0.y * b1.y + c0.z * b1.z + c0.w * b1.w;
      d10 += c1.x * b0.x + c1.y * b0.y + c1.z * b0.z + c1.w * b0.w;
      d11 += c1.x * b1.x + c1.y * b1.y + c1.z * b1.z + c1.w * b1.w;
    }
    {
      int lg0 = L0 + l0, lg1 = L0 + l0 + 16;
      int sg0 = sbase + s0, sg1 = sbase + s0 + 16;
      Wt[l0][s0]           = (sg0 <= lg0) ? d00 * __expf(sAc[lg0] - sAc[sg0]) : 0.f;
      Wt[l0][s0 + 16]      = (sg1 <= lg0) ? d01 * __expf(sAc[lg0] - sAc[sg1]) : 0.f;
      Wt[l0 + 16][s0]      = (sg0 <= lg1) ? d10 * __expf(sAc[lg1] - sAc[sg0]) : 0.f;
      Wt[l0 + 16][s0 + 16] = (sg1 <= lg1) ? d11 * __expf(sAc[lg1] - sAc[sg1]) : 0.f;
    }
    __syncthreads();
#pragma unroll
    for (int s = 0; s < 32; s++) {
      float hv = hst[s][p];
#pragma unroll
      for (int k = 0; k < 8; k++) acc[k] += Wt[rg + 4 * k][s] * hv;
    }
    __syncthreads();
  }
  size_t sinbase = ((size_t)(((b * NC + c) * NH + h) * HD)) * SSZ;
  float yoff[8] = {};
#pragma unroll
  for (int n4 = 0; n4 < 32; n4++) {
    float4 sv = *reinterpret_cast<const float4*>(&cs[sinbase + (size_t)p * SSZ + n4 * 4]);
#pragma unroll
    for (int k = 0; k < 8; k++) {
      float4 cv = *reinterpret_cast<const float4*>(&Ct[rg + 4 * k][n4 * 4]);
      yoff[k] += cv.x * sv.x + cv.y * sv.y + cv.z * sv.z + cv.w * sv.w;
    }
  }
  float Dh = Dp[h];
#pragma unroll
  for (int k = 0; k < 8; k++) {
    int lg = L0 + rg + 4 * k;
    int row = row0 + lg;
    float hplain = ldf(&convo[(size_t)row * CONV_DIM + h * HD + p]);
    yb[(size_t)row * INTER + h * HD + p] =
        __float2bfloat16(acc[k] + yoff[k] * __expf(sAc[lg]) + Dh * hplain);
  }
}

// ---------------- gate SiLU + RMSNorm (in-place on yb) ----------------
__global__ __launch_bounds__(256) void norm_k(const bf16* __restrict__ proj,
                                              const float* __restrict__ nw,
                                              bf16* __restrict__ yb) {
  int row = blockIdx.x;
  int tid = threadIdx.x;
  float vals[16];
  float ss = 0.f;
#pragma unroll
  for (int i = 0; i < 16; i++) {
    int col = tid + i * 256;
    float gt = ldf(&proj[(size_t)row * PROJ_DIM + col]);
    float yf = ldf(&yb[(size_t)row * INTER + col]) * siluf(gt);
    vals[i] = yf;
    ss += yf * yf;
  }
#pragma unroll
  for (int off = 32; off > 0; off >>= 1) ss += __shfl_down(ss, off);
  __shared__ float red[4];
  if ((tid & 63) == 0) red[tid >> 6] = ss;
  __syncthreads();
  float tot = red[0] + red[1] + red[2] + red[3];
  float scale = rsqrtf(tot * (1.f / INTER) + 1e-6f);
#pragma unroll
  for (int i = 0; i < 16; i++) {
    int col = tid + i * 256;
    yb[(size_t)row * INTER + col] = __float2bfloat16(vals[i] * scale * nw[col]);
  }
}

extern "C" void kernel_launch(void* const* d_in, const int* in_sizes, int n_in,
                              void* d_out, int out_size, void* d_ws, size_t ws_size,
                              hipStream_t stream) {
  const float* x     = (const float*)d_in[0];
  const float* wproj = (const float*)d_in[1];
  const float* cw    = (const float*)d_in[2];
  const float* cb    = (const float*)d_in[3];
  const float* dtb   = (const float*)d_in[4];
  const float* alog  = (const float*)d_in[5];
  const float* Dp    = (const float*)d_in[6];
  const float* nw    = (const float*)d_in[7];
  const float* wout  = (const float*)d_in[8];
  float* out = (float*)d_out;
  char* ws = (char*)d_ws;

  // workspace layout (bytes, all offsets 1 KiB aligned) — total 203,948,032 B ≈ 195 MiB
  bf16*  proj  = (bf16*)(ws);                    // 42,205,184 bf16 = 84,410,368 B
  bf16*  convo = (bf16*)(ws + 84410368);         // 25,165,824 bf16 = 50,331,648 B
  bf16*  yb    = (bf16*)(ws + 134742016);        // 16,777,216 bf16 = 33,554,432 B
  float* dtp   = (float*)(ws + 168296448);       //    262,144 f32  =  1,048,576 B
  float* acum  = (float*)(ws + 169345024);       //    262,144 f32  =  1,048,576 B
  float* cs    = (float*)(ws + 170393600);       //  8,388,608 f32  = 33,554,432 B

  gemm_t<float, bf16><<<dim3(PROJ_DIM / 64, ROWS / 64), 256, 0, stream>>>(x, wproj, proj, ROWS, PROJ_DIM, HIDDEN);
  conv_silu_k<<<dim3(ROWS * CONV_DIM / 256), 256, 0, stream>>>(proj, cw, cb, convo);
  dt_k<<<dim3(ROWS * NH / 256), 256, 0, stream>>>(proj, dtb, dtp);
  acum_k<<<dim3(2 * NH * NC), 256, 0, stream>>>(dtp, alog, acum);
  chunk_states_k<<<dim3(2 * NC * NH), 256, 0, stream>>>(convo, dtp, acum, cs);
  chunk_rec_k<<<dim3(2 * NH * HD * SSZ / 256), 256, 0, stream>>>(acum, cs);
  chunk_out_k<<<dim3(2 * NC * NH * 8), 256, 0, stream>>>(convo, dtp, acum, cs, Dp, yb);
  norm_k<<<dim3(ROWS), 256, 0, stream>>>(proj, nw, yb);
  gemm_t<bf16, float><<<dim3(HIDDEN / 64, ROWS / 64), 256, 0, stream>>>(yb, wout, out, ROWS, HIDDEN, INTER);
}

// Round 3
// 1562.350 us; speedup vs baseline: 5.3365x; 5.3365x over previous
//
#include <hip/hip_runtime.h>
#include <hip/hip_bf16.h>

// Mamba2 mixer — MFMA GEMMs + MFMA chunk_out. bf16 intermediates, fp32 accum.
// B=2 S=2048 HID=2048 INTER=4096 NH=64 HD=64 NG=8 SS=128 CK=4 CH=256 NC=8

#define S_LEN 2048
#define HIDDEN 2048
#define INTER 4096
#define NH 64
#define HD 64
#define NG 8
#define SSZ 128
#define CONV_DIM 6144
#define PROJ_DIM 10304
#define NC 8
#define CHK 256
#define ROWS 4096          // B*S
#define DT_OFF 10240       // INTER + CONV_DIM
#define B_OFF 4096         // B section inside conv block
#define C_OFF 5120         // C section inside conv block

typedef __hip_bfloat16 bf16;
typedef __attribute__((ext_vector_type(8))) short bf16x8;
typedef __attribute__((ext_vector_type(4))) float f32x4;
#define MFMA16(a, b, c) __builtin_amdgcn_mfma_f32_16x16x32_bf16(a, b, c, 0, 0, 0)

union U16x8 { uint4 u; bf16x8 v; };

__device__ __forceinline__ float siluf(float x) { return x / (1.f + __expf(-x)); }
__device__ __forceinline__ float ldf(const float* p) { return *p; }
__device__ __forceinline__ float ldf(const bf16* p) { return __bfloat162float(*p); }
__device__ __forceinline__ unsigned short f2bu(float x) {
  bf16 h = __float2bfloat16(x);
  return __builtin_bit_cast(unsigned short, h);
}
__device__ __forceinline__ float bu2f(unsigned short u) {
  return __uint_as_float(((unsigned)u) << 16);
}
__device__ __forceinline__ unsigned pack2(float lo, float hi) {
  return ((unsigned)f2bu(hi) << 16) | f2bu(lo);
}

// ================= MFMA GEMM: C[M,N] = A[M,K] @ W[K,N], W fp32 ==============
// 128x128 tile, BK=32, 256 threads (4 waves, 2x2), bf16 conversion in staging.
template <typename TA, typename TC>
__global__ __launch_bounds__(256) void gemm_mfma(const TA* __restrict__ A,
                                                 const float* __restrict__ W,
                                                 TC* __restrict__ C,
                                                 int M, int N, int K) {
  __shared__ unsigned short sA[128 * 40];  // [row][k] pad 40 (stride 80B)
  __shared__ unsigned short sB[128 * 40];  // [n][k]  pad 40
  const int tid = threadIdx.x;
  const int lane = tid & 63, hi = lane >> 4, sl = lane & 15;
  const int wid = tid >> 6, wm = wid >> 1, wn = wid & 1;
  const int m0 = blockIdx.y * 128;
  const int n0 = blockIdx.x * 128;
  const int arow = tid >> 1, ahalf = tid & 1;   // A staging: 16 elems/thread
  const int bk = tid >> 3, bseg = tid & 7;      // W staging: 16 elems/thread

  f32x4 acc[4][4] = {};
  for (int kt = 0; kt < K; kt += 32) {
    // ---- stage A tile [128][32] -> bf16 ----
    if constexpr (sizeof(TA) == 4) {
      const float* ar = &A[(size_t)(m0 + arow) * K + kt + ahalf * 16];
      unsigned dw[8];
#pragma unroll
      for (int f = 0; f < 4; ++f) {
        float4 v = *reinterpret_cast<const float4*>(ar + f * 4);
        dw[f * 2]     = pack2(v.x, v.y);
        dw[f * 2 + 1] = pack2(v.z, v.w);
      }
      *reinterpret_cast<uint4*>(&sA[arow * 40 + ahalf * 16]) =
          make_uint4(dw[0], dw[1], dw[2], dw[3]);
      *reinterpret_cast<uint4*>(&sA[arow * 40 + ahalf * 16 + 8]) =
          make_uint4(dw[4], dw[5], dw[6], dw[7]);
    } else {
      const uint4* ar = reinterpret_cast<const uint4*>(&A[(size_t)(m0 + arow) * K + kt + ahalf * 16]);
      *reinterpret_cast<uint4*>(&sA[arow * 40 + ahalf * 16]) = ar[0];
      *reinterpret_cast<uint4*>(&sA[arow * 40 + ahalf * 16 + 8]) = ar[1];
    }
    // ---- stage W tile [32][128] transposed -> sB[n][k], zero-pad n>=N ----
    {
      const float* wr = &W[(size_t)(kt + bk) * N + n0 + bseg * 16];
      float tmp[16];
#pragma unroll
      for (int f = 0; f < 4; ++f) {
        int ng = n0 + bseg * 16 + f * 4;
        float4 v = (ng + 3 < N) ? *reinterpret_cast<const float4*>(wr + f * 4)
                                : make_float4(0.f, 0.f, 0.f, 0.f);
        tmp[f * 4 + 0] = v.x; tmp[f * 4 + 1] = v.y;
        tmp[f * 4 + 2] = v.z; tmp[f * 4 + 3] = v.w;
      }
#pragma unroll
      for (int j = 0; j < 16; ++j) {
        int jj = (j + lane) & 15;  // stagger to spread banks
        sB[(bseg * 16 + jj) * 40 + bk] = f2bu(tmp[jj]);
      }
    }
    __syncthreads();
    // ---- fragments + 16 MFMA ----
    bf16x8 af[4], bfv[4];
#pragma unroll
    for (int m = 0; m < 4; ++m)
      af[m] = *reinterpret_cast<const bf16x8*>(&sA[(wm * 64 + m * 16 + sl) * 40 + hi * 8]);
#pragma unroll
    for (int j = 0; j < 4; ++j)
      bfv[j] = *reinterpret_cast<const bf16x8*>(&sB[(wn * 64 + j * 16 + sl) * 40 + hi * 8]);
#pragma unroll
    for (int m = 0; m < 4; ++m)
#pragma unroll
      for (int j = 0; j < 4; ++j)
        acc[m][j] = MFMA16(af[m], bfv[j], acc[m][j]);
    __syncthreads();
  }
  // ---- store (col-guarded) ----
#pragma unroll
  for (int m = 0; m < 4; ++m)
#pragma unroll
    for (int j = 0; j < 4; ++j)
#pragma unroll
      for (int r = 0; r < 4; ++r) {
        int row = m0 + wm * 64 + m * 16 + hi * 4 + r;
        int col = n0 + wn * 64 + j * 16 + sl;
        if (col < N) {
          float v = acc[m][j][r];
          if constexpr (sizeof(TC) == 2)
            C[(size_t)row * N + col] = __float2bfloat16(v);
          else
            C[(size_t)row * N + col] = v;
        }
      }
}

// ---------------- depthwise conv (SAME, k=4, pad_lo=1) + SiLU ----------------
__global__ __launch_bounds__(256) void conv_silu_k(const bf16* __restrict__ proj,
                                                   const float* __restrict__ cw,
                                                   const float* __restrict__ cb,
                                                   bf16* __restrict__ convo) {
  int idx = blockIdx.x * 256 + threadIdx.x;
  int c = idx % CONV_DIM;
  int row = idx / CONV_DIM;
  int t = row & (S_LEN - 1);
  int b = row >> 11;
  float acc = cb[c];
#pragma unroll
  for (int w = 0; w < 4; w++) {
    int tt = t + w - 1;
    if (tt >= 0 && tt < S_LEN)
      acc += cw[w * CONV_DIM + c] * ldf(&proj[(size_t)(b * S_LEN + tt) * PROJ_DIM + INTER + c]);
  }
  convo[idx] = __float2bfloat16(siluf(acc));
}

// ---------------- dt = softplus(dt_raw + dt_bias) ----------------
__global__ __launch_bounds__(256) void dt_k(const bf16* __restrict__ proj,
                                            const float* __restrict__ dtb,
                                            float* __restrict__ dtp) {
  int idx = blockIdx.x * 256 + threadIdx.x;
  int h = idx & 63;
  int row = idx >> 6;
  float x = ldf(&proj[(size_t)row * PROJ_DIM + DT_OFF + h]) + dtb[h];
  dtp[idx] = (x > 20.f) ? x : log1pf(__expf(x));
}

// ---------------- per-chunk cumsum of A[h]*dt ----------------
__global__ __launch_bounds__(256) void acum_k(const float* __restrict__ dtp,
                                              const float* __restrict__ alog,
                                              float* __restrict__ acum) {
  __shared__ float buf[2][CHK];
  int blk = blockIdx.x;
  int c = blk & 7;
  int h = (blk >> 3) & 63;
  int b = blk >> 9;
  int tid = threadIdx.x;
  int row0 = b * S_LEN + c * CHK;
  float a = -__expf(alog[h]);
  buf[0][tid] = a * dtp[(size_t)(row0 + tid) * NH + h];
  __syncthreads();
  int cur = 0;
#pragma unroll
  for (int off = 1; off < 256; off <<= 1) {
    float nv = buf[cur][tid];
    if (tid >= off) nv += buf[cur][tid - off];
    buf[cur ^ 1][tid] = nv;
    cur ^= 1;
    __syncthreads();
  }
  acum[(size_t)blk * CHK + tid] = buf[cur][tid];
}

// ---------------- per-chunk states (fp32) ----------------
__global__ __launch_bounds__(256) void chunk_states_k(const bf16* __restrict__ convo,
                                                      const float* __restrict__ dtp,
                                                      const float* __restrict__ acum,
                                                      float* __restrict__ cs) {
  __shared__ float sAc[CHK];
  __shared__ float sDt[CHK];
  __shared__ __align__(16) float hst[64][68];
  __shared__ __align__(16) float Bd[64][132];
  int blk = blockIdx.x;
  int h = blk & 63;
  int bc = blk >> 6;
  int c = bc & 7;
  int b = bc >> 3;
  int g = h >> 3;
  int tid = threadIdx.x;
  int row0 = b * S_LEN + c * CHK;
  sAc[tid] = acum[((size_t)((b * NH + h) * NC + c)) * CHK + tid];
  sDt[tid] = dtp[(size_t)(row0 + tid) * NH + h];
  __syncthreads();
  float alast = sAc[CHK - 1];
  int tx = tid & 31, ty = tid >> 5;
  float acc[8][4] = {};
  for (int ts = 0; ts < CHK; ts += 64) {
#pragma unroll
    for (int i = 0; i < 16; i++) {
      int idx = tid + i * 256;
      int t = idx >> 6, p = idx & 63;
      hst[t][p] = ldf(&convo[(size_t)(row0 + ts + t) * CONV_DIM + h * HD + p]) * sDt[ts + t];
    }
#pragma unroll
    for (int i = 0; i < 32; i++) {
      int idx = tid + i * 256;
      int t = idx >> 7, n = idx & 127;
      Bd[t][n] = ldf(&convo[(size_t)(row0 + ts + t) * CONV_DIM + B_OFF + g * SSZ + n]) *
                 __expf(alast - sAc[ts + t]);
    }
    __syncthreads();
#pragma unroll
    for (int t = 0; t < 64; t++) {
      float4 bv = *reinterpret_cast<const float4*>(&Bd[t][tx * 4]);
#pragma unroll
      for (int k = 0; k < 8; k++) {
        float hv = hst[t][ty + 8 * k];
        acc[k][0] += hv * bv.x; acc[k][1] += hv * bv.y;
        acc[k][2] += hv * bv.z; acc[k][3] += hv * bv.w;
      }
    }
    __syncthreads();
  }
  size_t base = (size_t)blk * HD * SSZ;  // [b][c][h][p][n]
#pragma unroll
  for (int k = 0; k < 8; k++) {
    float4 v = make_float4(acc[k][0], acc[k][1], acc[k][2], acc[k][3]);
    *reinterpret_cast<float4*>(&cs[base + (size_t)(ty + 8 * k) * SSZ + tx * 4]) = v;
  }
}

// ---------------- inter-chunk recurrence (in-place) ----------------
__global__ __launch_bounds__(256) void chunk_rec_k(const float* __restrict__ acum,
                                                   float* __restrict__ cs) {
  int idx = blockIdx.x * 256 + threadIdx.x;
  int n = idx & 127;
  int p = (idx >> 7) & 63;
  int h = (idx >> 13) & 63;
  int b = idx >> 19;
  float run = 0.f;
#pragma unroll
  for (int c = 0; c < NC; c++) {
    size_t off = ((size_t)(((b * NC + c) * NH + h) * HD + p)) * SSZ + n;
    float csv = cs[off];
    float al = acum[((size_t)((b * NH + h) * NC + c)) * CHK + (CHK - 1)];
    cs[off] = run;
    run = run * __expf(al) + csv;
  }
}

// ================= chunk output via MFMA (flash-style) =======================
// 1 block per (b,c,h); wave w owns l-rows [w*64, w*64+64).
__global__ __launch_bounds__(256) void chunk_out_mfma(const bf16* __restrict__ convo,
                                                      const float* __restrict__ dtp,
                                                      const float* __restrict__ acum,
                                                      const float* __restrict__ cs,
                                                      const float* __restrict__ Dp,
                                                      bf16* __restrict__ yb) {
  __shared__ float sAc[CHK];                      // 1 KB
  __shared__ float sDt[CHK];                      // 1 KB
  __shared__ __align__(16) unsigned short sB[64 * 128];       // 16 KB  B-tile / Sin, XOR-swz
  __shared__ __align__(16) unsigned short sH[64 * 64];        // 8 KB   hsdt^T [p][s], XOR-swz
  __shared__ __align__(16) unsigned short sW[4 * 64 * 64];    // 32 KB  per-wave W [l][s], XOR-swz
  const int tid = threadIdx.x;
  const int lane = tid & 63, hi = lane >> 4, sl = lane & 15;
  const int wid = tid >> 6;
  const int blk = blockIdx.x;
  const int h = blk & 63;
  const int bc = blk >> 6;
  const int c = bc & 7;
  const int b = bc >> 3;
  const int g = h >> 3;
  const int row0 = b * S_LEN + c * CHK;
  unsigned short* sWp = &sW[wid * 4096];

  sAc[tid] = acum[((size_t)((b * NH + h) * NC + c)) * CHK + tid];
  sDt[tid] = dtp[(size_t)(row0 + tid) * NH + h];

  // C fragments (A operand), persistent in registers: rows wid*64.., K=n 0..128
  bf16x8 cf[4][4];
#pragma unroll
  for (int m = 0; m < 4; ++m)
#pragma unroll
    for (int kc = 0; kc < 4; ++kc) {
      int l = wid * 64 + m * 16 + sl;
      U16x8 u;
      u.u = *reinterpret_cast<const uint4*>(
          &convo[(size_t)(row0 + l) * CONV_DIM + C_OFF + g * SSZ + kc * 32 + hi * 8]);
      cf[m][kc] = u.v;
    }

  f32x4 acc[4][4] = {};

  for (int st = 0; st < 4; ++st) {
    __syncthreads();   // protect sB/sH from previous readers; covers prologue at st=0
    // ---- stage B tile [s][n] (64x128 bf16), XOR-swizzled 16B granules ----
#pragma unroll
    for (int it = 0; it < 4; ++it) {
      int cid = tid + it * 256;          // 1024 granules
      int s = cid >> 4, gr = cid & 15;
      const uint4* p = reinterpret_cast<const uint4*>(
          &convo[(size_t)(row0 + st * 64 + s) * CONV_DIM + B_OFF + g * SSZ + gr * 8]);
      *reinterpret_cast<uint4*>(&sB[s * 128 + (gr ^ (s & 7)) * 8]) = *p;
    }
    // ---- stage hsdt^T [p][s] (64x64 bf16) ----
#pragma unroll
    for (int it = 0; it < 16; ++it) {
      int cid = tid + it * 256;          // 4096 elems
      int s = cid >> 6, pp = cid & 63;
      float v = ldf(&convo[(size_t)(row0 + st * 64 + s) * CONV_DIM + h * HD + pp]) *
                sDt[st * 64 + s];
      sH[pp * 64 + (((s >> 3) ^ (pp & 7)) * 8) + (s & 7)] = f2bu(v);
    }
    __syncthreads();
    // ---- scores: W = mask(C·B^T) * exp(Ac[l]-Ac[s]) -> sW (bf16) ----
    if (wid >= st) {
#pragma unroll
      for (int sf = 0; sf < 4; ++sf) {
        f32x4 d[4] = {};
#pragma unroll
        for (int kc = 0; kc < 4; ++kc) {
          int srow = sf * 16 + sl;
          bf16x8 bfv = *reinterpret_cast<const bf16x8*>(
              &sB[srow * 128 + (((kc * 4 + hi) ^ (srow & 7)) * 8)]);
#pragma unroll
          for (int m = 0; m < 4; ++m) d[m] = MFMA16(cf[m][kc], bfv, d[m]);
        }
        int s_loc = sf * 16 + sl;
        int s_glob = st * 64 + s_loc;
        float acS = sAc[s_glob];
        bool diag = (st == wid);
#pragma unroll
        for (int m = 0; m < 4; ++m)
#pragma unroll
          for (int r = 0; r < 4; ++r) {
            int l_loc = m * 16 + hi * 4 + r;
            int l_glob = wid * 64 + l_loc;
            float e = __expf(sAc[l_glob] - acS);
            float v = d[m][r] * e;
            if (diag && s_glob > l_glob) v = 0.f;
            sWp[l_loc * 64 + (((s_loc >> 3) ^ (l_loc & 7)) * 8) + (s_loc & 7)] = f2bu(v);
          }
      }
    }
    __syncthreads();
    // ---- PV: acc += W(64xs64) * hsdt(s64x64) ----
    if (wid >= st) {
#pragma unroll
      for (int kc = 0; kc < 2; ++kc) {
        bf16x8 a[4], bb[4];
#pragma unroll
        for (int m = 0; m < 4; ++m) {
          int l = m * 16 + sl;
          a[m] = *reinterpret_cast<const bf16x8*>(
              &sWp[l * 64 + (((kc * 4 + hi) ^ (l & 7)) * 8)]);
        }
#pragma unroll
        for (int j = 0; j < 4; ++j) {
          int p = j * 16 + sl;
          bb[j] = *reinterpret_cast<const bf16x8*>(
              &sH[p * 64 + (((kc * 4 + hi) ^ (p & 7)) * 8)]);
        }
#pragma unroll
        for (int m = 0; m < 4; ++m)
#pragma unroll
          for (int j = 0; j < 4; ++j) acc[m][j] = MFMA16(a[m], bb[j], acc[m][j]);
      }
    }
  }

  // ---- Y_off: stage Sin (f32 -> bf16, [p][n]) into sB, then acc += Cs·Sin^T --
  __syncthreads();
  {
    size_t sinbase = ((size_t)(((b * NC + c) * NH + h) * HD)) * SSZ;
#pragma unroll
    for (int it = 0; it < 8; ++it) {
      int cid = tid + it * 256;          // 2048 float4 chunks
      int p = cid >> 5, q = cid & 31;
      float4 v = *reinterpret_cast<const float4*>(&cs[sinbase + (size_t)p * SSZ + q * 4]);
      uint2 val = make_uint2(pack2(v.x, v.y), pack2(v.z, v.w));
      *reinterpret_cast<uint2*>(&sB[p * 128 + ((q >> 1) ^ (p & 7)) * 8 + (q & 1) * 4]) = val;
    }
  }
  __syncthreads();
  // pre-scale C-frags by exp(Ac[l]) (row-uniform per lane)
#pragma unroll
  for (int m = 0; m < 4; ++m) {
    float e = __expf(sAc[wid * 64 + m * 16 + sl]);
#pragma unroll
    for (int kc = 0; kc < 4; ++kc) {
      bf16x8 fv = cf[m][kc];
#pragma unroll
      for (int ei = 0; ei < 8; ++ei) {
        unsigned short us = (unsigned short)fv[ei];
        fv[ei] = (short)f2bu(bu2f(us) * e);
      }
      cf[m][kc] = fv;
    }
  }
#pragma unroll
  for (int kc = 0; kc < 4; ++kc) {
    bf16x8 bb[4];
#pragma unroll
    for (int j = 0; j < 4; ++j) {
      int p = j * 16 + sl;
      bb[j] = *reinterpret_cast<const bf16x8*>(
          &sB[p * 128 + (((kc * 4 + hi) ^ (p & 7)) * 8)]);
    }
#pragma unroll
    for (int m = 0; m < 4; ++m)
#pragma unroll
      for (int j = 0; j < 4; ++j) acc[m][j] = MFMA16(cf[m][kc], bb[j], acc[m][j]);
  }

  // ---- epilogue: + D*hs_raw, store bf16 ----
  float Dh = Dp[h];
#pragma unroll
  for (int m = 0; m < 4; ++m)
#pragma unroll
    for (int j = 0; j < 4; ++j)
#pragma unroll
      for (int r = 0; r < 4; ++r) {
        int l_glob = wid * 64 + m * 16 + hi * 4 + r;
        size_t row = (size_t)(row0 + l_glob);
        int pg = j * 16 + sl;
        float hraw = ldf(&convo[row * CONV_DIM + h * HD + pg]);
        yb[row * INTER + h * HD + pg] = __float2bfloat16(acc[m][j][r] + Dh * hraw);
      }
}

// ---------------- gate SiLU + RMSNorm (in-place on yb) ----------------
__global__ __launch_bounds__(256) void norm_k(const bf16* __restrict__ proj,
                                              const float* __restrict__ nw,
                                              bf16* __restrict__ yb) {
  int row = blockIdx.x;
  int tid = threadIdx.x;
  float vals[16];
  float ss = 0.f;
#pragma unroll
  for (int i = 0; i < 16; i++) {
    int col = tid + i * 256;
    float gt = ldf(&proj[(size_t)row * PROJ_DIM + col]);
    float yf = ldf(&yb[(size_t)row * INTER + col]) * siluf(gt);
    vals[i] = yf;
    ss += yf * yf;
  }
#pragma unroll
  for (int off = 32; off > 0; off >>= 1) ss += __shfl_down(ss, off);
  __shared__ float red[4];
  if ((tid & 63) == 0) red[tid >> 6] = ss;
  __syncthreads();
  float tot = red[0] + red[1] + red[2] + red[3];
  float scale = rsqrtf(tot * (1.f / INTER) + 1e-6f);
#pragma unroll
  for (int i = 0; i < 16; i++) {
    int col = tid + i * 256;
    yb[(size_t)row * INTER + col] = __float2bfloat16(vals[i] * scale * nw[col]);
  }
}

extern "C" void kernel_launch(void* const* d_in, const int* in_sizes, int n_in,
                              void* d_out, int out_size, void* d_ws, size_t ws_size,
                              hipStream_t stream) {
  const float* x     = (const float*)d_in[0];
  const float* wproj = (const float*)d_in[1];
  const float* cw    = (const float*)d_in[2];
  const float* cb    = (const float*)d_in[3];
  const float* dtb   = (const float*)d_in[4];
  const float* alog  = (const float*)d_in[5];
  const float* Dp    = (const float*)d_in[6];
  const float* nw    = (const float*)d_in[7];
  const float* wout  = (const float*)d_in[8];
  float* out = (float*)d_out;
  char* ws = (char*)d_ws;

  // workspace layout (same proven footprint, ~195 MiB)
  bf16*  proj  = (bf16*)(ws);                    // 42,205,184 bf16
  bf16*  convo = (bf16*)(ws + 84410368);         // 25,165,824 bf16
  bf16*  yb    = (bf16*)(ws + 134742016);        // 16,777,216 bf16
  float* dtp   = (float*)(ws + 168296448);       //    262,144 f32
  float* acum  = (float*)(ws + 169345024);       //    262,144 f32
  float* cs    = (float*)(ws + 170393600);       //  8,388,608 f32

  gemm_mfma<float, bf16><<<dim3((PROJ_DIM + 127) / 128, ROWS / 128), 256, 0, stream>>>(
      x, wproj, proj, ROWS, PROJ_DIM, HIDDEN);
  conv_silu_k<<<dim3(ROWS * CONV_DIM / 256), 256, 0, stream>>>(proj, cw, cb, convo);
  dt_k<<<dim3(ROWS * NH / 256), 256, 0, stream>>>(proj, dtb, dtp);
  acum_k<<<dim3(2 * NH * NC), 256, 0, stream>>>(dtp, alog, acum);
  chunk_states_k<<<dim3(2 * NC * NH), 256, 0, stream>>>(convo, dtp, acum, cs);
  chunk_rec_k<<<dim3(2 * NH * HD * SSZ / 256), 256, 0, stream>>>(acum, cs);
  chunk_out_mfma<<<dim3(2 * NC * NH), 256, 0, stream>>>(convo, dtp, acum, cs, Dp, yb);
  norm_k<<<dim3(ROWS), 256, 0, stream>>>(proj, nw, yb);
  gemm_mfma<bf16, float><<<dim3(HIDDEN / 128, ROWS / 128), 256, 0, stream>>>(
      yb, wout, out, ROWS, HIDDEN, INTER);
}

// Round 5
// 697.941 us; speedup vs baseline: 11.9459x; 2.2385x over previous
//
#include <hip/hip_runtime.h>
#include <hip/hip_bf16.h>

// Mamba2 mixer — bf16 MFMA GEMMs w/ global_load_lds + swizzle; MFMA chunk_out.
// B=2 S=2048 HID=2048 INTER=4096 NH=64 HD=64 NG=8 SS=128 CK=4 CH=256 NC=8

#define S_LEN 2048
#define HIDDEN 2048
#define INTER 4096
#define NH 64
#define HD 64
#define NG 8
#define SSZ 128
#define CONV_DIM 6144
#define PROJ_DIM 10304
#define PROJ_PAD 10368     // 81*128
#define NC 8
#define CHK 256
#define ROWS 4096          // B*S
#define DT_OFF 10240       // INTER + CONV_DIM
#define B_OFF 4096         // B section inside conv block
#define C_OFF 5120         // C section inside conv block

typedef __hip_bfloat16 bf16;
typedef __attribute__((ext_vector_type(8))) short bf16x8;
typedef __attribute__((ext_vector_type(4))) float f32x4;
#define MFMA16(a, b, c) __builtin_amdgcn_mfma_f32_16x16x32_bf16(a, b, c, 0, 0, 0)

union U16x8 { uint4 u; bf16x8 v; };

__device__ __forceinline__ float siluf(float x) { return x / (1.f + __expf(-x)); }
__device__ __forceinline__ float ldf(const float* p) { return *p; }
__device__ __forceinline__ float ldf(const bf16* p) { return __bfloat162float(*p); }
__device__ __forceinline__ unsigned short f2bu(float x) {
  bf16 h = __float2bfloat16(x);
  return __builtin_bit_cast(unsigned short, h);
}
__device__ __forceinline__ float bu2f(unsigned short u) {
  return __uint_as_float(((unsigned)u) << 16);
}
__device__ __forceinline__ unsigned pack2(float lo, float hi) {
  return ((unsigned)f2bu(hi) << 16) | f2bu(lo);
}
// async global->LDS, 16B per lane; lptr must be wave-uniform (HW adds lane*16)
__device__ __forceinline__ void gload16(const void* g, void* l) {
  __builtin_amdgcn_global_load_lds((const __attribute__((address_space(1))) unsigned*)g,
                                   (__attribute__((address_space(3))) unsigned*)l, 16, 0, 0);
}

// ---------------- fp32 -> bf16 bulk convert (float4 granularity) ----------------
__global__ __launch_bounds__(256) void cvt_bf16_k(const float* __restrict__ x,
                                                  unsigned short* __restrict__ o, int n4) {
  int idx = blockIdx.x * 256 + threadIdx.x;
  int stride = gridDim.x * 256;
  for (int i = idx; i < n4; i += stride) {
    float4 v = reinterpret_cast<const float4*>(x)[i];
    uint2 u = make_uint2(pack2(v.x, v.y), pack2(v.z, v.w));
    reinterpret_cast<uint2*>(o)[i] = u;
  }
}

// ------------- weight transpose+convert: W[K][N] f32 -> Wt[NP][K] bf16 ----------
__global__ __launch_bounds__(256) void wT_k(const float* __restrict__ W,
                                            unsigned short* __restrict__ Wt,
                                            int K, int N) {
  __shared__ unsigned short t[64][72];
  int n0 = blockIdx.x * 64, k0 = blockIdx.y * 64;
  int tid = threadIdx.x;
#pragma unroll
  for (int i = 0; i < 16; ++i) {
    int idx = tid + i * 256;
    int kr = idx >> 6, nc = idx & 63;
    float v = (n0 + nc < N) ? W[(size_t)(k0 + kr) * N + n0 + nc] : 0.f;
    t[kr][nc] = f2bu(v);
  }
  __syncthreads();
#pragma unroll
  for (int i = 0; i < 16; ++i) {
    int idx = tid + i * 256;
    int nr = idx >> 6, kc = idx & 63;
    Wt[(size_t)(n0 + nr) * K + k0 + kc] = t[kc][nr];
  }
}

// ================= bf16 MFMA GEMM: C[M,N] = A[M,K] @ Wt[N,K]^T ==============
// 128x128 tile, BK=64, 256 threads (4 waves 2x2). global_load_lds staging with
// pre-swizzled source (slot ^= row&7), conflict-free ds_read_b128 fragments.
template <typename TC>
__global__ __launch_bounds__(256) void gemm_bf16(const unsigned short* __restrict__ A,
                                                 const unsigned short* __restrict__ Bt,
                                                 TC* __restrict__ C,
                                                 int M, int N, int K) {
  __shared__ __align__(16) unsigned short sA[128 * 64];  // [row][64] 128B rows
  __shared__ __align__(16) unsigned short sB[128 * 64];
  const int tid = threadIdx.x;
  const int lane = tid & 63, hi = lane >> 4, sl = lane & 15;
  const int wid = tid >> 6, wm = wid >> 1, wn = wid & 1;
  const int m0 = blockIdx.y * 128;
  const int n0 = blockIdx.x * 128;
  const int lrow = lane >> 3;   // row within 8-row chunk
  const int lslot = lane & 7;   // 16B slot within 128B row

  f32x4 acc[4][4] = {};
  for (int kt = 0; kt < K; kt += 64) {
    __syncthreads();  // protect LDS from prev-iter readers
#pragma unroll
    for (int i = 0; i < 4; ++i) {
      int c = wid * 4 + i;               // 1KB chunk id (16 total)
      int r = c * 8 + lrow;              // tile row this lane stages
      int g = lslot ^ (r & 7);           // inverse-swizzled source granule
      gload16(&A[(size_t)(m0 + r) * K + kt + g * 8], &sA[c * 512]);
      gload16(&Bt[(size_t)(n0 + r) * K + kt + g * 8], &sB[c * 512]);
    }
    __syncthreads();  // drains vmcnt(0) -> tiles resident
#pragma unroll
    for (int su = 0; su < 2; ++su) {
      bf16x8 af[4], bfr[4];
#pragma unroll
      for (int m = 0; m < 4; ++m) {
        int r = wm * 64 + m * 16 + sl;
        af[m] = *reinterpret_cast<const bf16x8*>(
            &sA[r * 64 + (((su * 4 + hi) ^ (sl & 7)) * 8)]);
      }
#pragma unroll
      for (int j = 0; j < 4; ++j) {
        int r = wn * 64 + j * 16 + sl;
        bfr[j] = *reinterpret_cast<const bf16x8*>(
            &sB[r * 64 + (((su * 4 + hi) ^ (sl & 7)) * 8)]);
      }
#pragma unroll
      for (int m = 0; m < 4; ++m)
#pragma unroll
        for (int j = 0; j < 4; ++j)
          acc[m][j] = MFMA16(af[m], bfr[j], acc[m][j]);
    }
  }
#pragma unroll
  for (int m = 0; m < 4; ++m)
#pragma unroll
    for (int j = 0; j < 4; ++j) {
      int col = n0 + wn * 64 + j * 16 + sl;
      if (col < N) {
#pragma unroll
        for (int r = 0; r < 4; ++r) {
          int row = m0 + wm * 64 + m * 16 + hi * 4 + r;
          if constexpr (sizeof(TC) == 2)
            C[(size_t)row * N + col] = __float2bfloat16(acc[m][j][r]);
          else
            C[(size_t)row * N + col] = acc[m][j][r];
        }
      }
    }
}

// ---------------- depthwise conv (SAME, k=4, pad_lo=1) + SiLU ----------------
__global__ __launch_bounds__(256) void conv_silu_k(const bf16* __restrict__ proj,
                                                   const float* __restrict__ cw,
                                                   const float* __restrict__ cb,
                                                   bf16* __restrict__ convo) {
  int idx = blockIdx.x * 256 + threadIdx.x;
  int c = idx % CONV_DIM;
  int row = idx / CONV_DIM;
  int t = row & (S_LEN - 1);
  int b = row >> 11;
  float acc = cb[c];
#pragma unroll
  for (int w = 0; w < 4; w++) {
    int tt = t + w - 1;
    if (tt >= 0 && tt < S_LEN)
      acc += cw[w * CONV_DIM + c] * ldf(&proj[(size_t)(b * S_LEN + tt) * PROJ_DIM + INTER + c]);
  }
  convo[idx] = __float2bfloat16(siluf(acc));
}

// ---------------- dt = softplus(dt_raw + dt_bias) ----------------
__global__ __launch_bounds__(256) void dt_k(const bf16* __restrict__ proj,
                                            const float* __restrict__ dtb,
                                            float* __restrict__ dtp) {
  int idx = blockIdx.x * 256 + threadIdx.x;
  int h = idx & 63;
  int row = idx >> 6;
  float x = ldf(&proj[(size_t)row * PROJ_DIM + DT_OFF + h]) + dtb[h];
  dtp[idx] = (x > 20.f) ? x : log1pf(__expf(x));
}

// ---------------- per-chunk cumsum of A[h]*dt ----------------
__global__ __launch_bounds__(256) void acum_k(const float* __restrict__ dtp,
                                              const float* __restrict__ alog,
                                              float* __restrict__ acum) {
  __shared__ float buf[2][CHK];
  int blk = blockIdx.x;
  int c = blk & 7;
  int h = (blk >> 3) & 63;
  int b = blk >> 9;
  int tid = threadIdx.x;
  int row0 = b * S_LEN + c * CHK;
  float a = -__expf(alog[h]);
  buf[0][tid] = a * dtp[(size_t)(row0 + tid) * NH + h];
  __syncthreads();
  int cur = 0;
#pragma unroll
  for (int off = 1; off < 256; off <<= 1) {
    float nv = buf[cur][tid];
    if (tid >= off) nv += buf[cur][tid - off];
    buf[cur ^ 1][tid] = nv;
    cur ^= 1;
    __syncthreads();
  }
  acum[(size_t)blk * CHK + tid] = buf[cur][tid];
}

// ---------------- per-chunk states (fp32) ----------------
__global__ __launch_bounds__(256) void chunk_states_k(const bf16* __restrict__ convo,
                                                      const float* __restrict__ dtp,
                                                      const float* __restrict__ acum,
                                                      float* __restrict__ cs) {
  __shared__ float sAc[CHK];
  __shared__ float sDt[CHK];
  __shared__ __align__(16) float hst[64][68];
  __shared__ __align__(16) float Bd[64][132];
  int blk = blockIdx.x;
  int h = blk & 63;
  int bc = blk >> 6;
  int c = bc & 7;
  int b = bc >> 3;
  int g = h >> 3;
  int tid = threadIdx.x;
  int row0 = b * S_LEN + c * CHK;
  sAc[tid] = acum[((size_t)((b * NH + h) * NC + c)) * CHK + tid];
  sDt[tid] = dtp[(size_t)(row0 + tid) * NH + h];
  __syncthreads();
  float alast = sAc[CHK - 1];
  int tx = tid & 31, ty = tid >> 5;
  float acc[8][4] = {};
  for (int ts = 0; ts < CHK; ts += 64) {
#pragma unroll
    for (int i = 0; i < 16; i++) {
      int idx = tid + i * 256;
      int t = idx >> 6, p = idx & 63;
      hst[t][p] = ldf(&convo[(size_t)(row0 + ts + t) * CONV_DIM + h * HD + p]) * sDt[ts + t];
    }
#pragma unroll
    for (int i = 0; i < 32; i++) {
      int idx = tid + i * 256;
      int t = idx >> 7, n = idx & 127;
      Bd[t][n] = ldf(&convo[(size_t)(row0 + ts + t) * CONV_DIM + B_OFF + g * SSZ + n]) *
                 __expf(alast - sAc[ts + t]);
    }
    __syncthreads();
#pragma unroll
    for (int t = 0; t < 64; t++) {
      float4 bv = *reinterpret_cast<const float4*>(&Bd[t][tx * 4]);
#pragma unroll
      for (int k = 0; k < 8; k++) {
        float hv = hst[t][ty + 8 * k];
        acc[k][0] += hv * bv.x; acc[k][1] += hv * bv.y;
        acc[k][2] += hv * bv.z; acc[k][3] += hv * bv.w;
      }
    }
    __syncthreads();
  }
  size_t base = (size_t)blk * HD * SSZ;  // [b][c][h][p][n]
#pragma unroll
  for (int k = 0; k < 8; k++) {
    float4 v = make_float4(acc[k][0], acc[k][1], acc[k][2], acc[k][3]);
    *reinterpret_cast<float4*>(&cs[base + (size_t)(ty + 8 * k) * SSZ + tx * 4]) = v;
  }
}

// ---------------- inter-chunk recurrence (in-place) ----------------
__global__ __launch_bounds__(256) void chunk_rec_k(const float* __restrict__ acum,
                                                   float* __restrict__ cs) {
  int idx = blockIdx.x * 256 + threadIdx.x;
  int n = idx & 127;
  int p = (idx >> 7) & 63;
  int h = (idx >> 13) & 63;
  int b = idx >> 19;
  float run = 0.f;
#pragma unroll
  for (int c = 0; c < NC; c++) {
    size_t off = ((size_t)(((b * NC + c) * NH + h) * HD + p)) * SSZ + n;
    float csv = cs[off];
    float al = acum[((size_t)((b * NH + h) * NC + c)) * CHK + (CHK - 1)];
    cs[off] = run;
    run = run * __expf(al) + csv;
  }
}

// ================= chunk output via MFMA (flash-style) =======================
__global__ __launch_bounds__(256) void chunk_out_mfma(const bf16* __restrict__ convo,
                                                      const float* __restrict__ dtp,
                                                      const float* __restrict__ acum,
                                                      const float* __restrict__ cs,
                                                      const float* __restrict__ Dp,
                                                      bf16* __restrict__ yb) {
  __shared__ float sAc[CHK];
  __shared__ float sDt[CHK];
  __shared__ __align__(16) unsigned short sB[64 * 128];
  __shared__ __align__(16) unsigned short sH[64 * 64];
  __shared__ __align__(16) unsigned short sW[4 * 64 * 64];
  const int tid = threadIdx.x;
  const int lane = tid & 63, hi = lane >> 4, sl = lane & 15;
  const int wid = tid >> 6;
  const int blk = blockIdx.x;
  const int h = blk & 63;
  const int bc = blk >> 6;
  const int c = bc & 7;
  const int b = bc >> 3;
  const int g = h >> 3;
  const int row0 = b * S_LEN + c * CHK;
  unsigned short* sWp = &sW[wid * 4096];

  sAc[tid] = acum[((size_t)((b * NH + h) * NC + c)) * CHK + tid];
  sDt[tid] = dtp[(size_t)(row0 + tid) * NH + h];

  bf16x8 cf[4][4];
#pragma unroll
  for (int m = 0; m < 4; ++m)
#pragma unroll
    for (int kc = 0; kc < 4; ++kc) {
      int l = wid * 64 + m * 16 + sl;
      U16x8 u;
      u.u = *reinterpret_cast<const uint4*>(
          &convo[(size_t)(row0 + l) * CONV_DIM + C_OFF + g * SSZ + kc * 32 + hi * 8]);
      cf[m][kc] = u.v;
    }

  f32x4 acc[4][4] = {};

  for (int st = 0; st < 4; ++st) {
    __syncthreads();
#pragma unroll
    for (int it = 0; it < 4; ++it) {
      int cid = tid + it * 256;
      int s = cid >> 4, gr = cid & 15;
      const uint4* p = reinterpret_cast<const uint4*>(
          &convo[(size_t)(row0 + st * 64 + s) * CONV_DIM + B_OFF + g * SSZ + gr * 8]);
      *reinterpret_cast<uint4*>(&sB[s * 128 + (gr ^ (s & 7)) * 8]) = *p;
    }
#pragma unroll
    for (int it = 0; it < 16; ++it) {
      int cid = tid + it * 256;
      int s = cid >> 6, pp = cid & 63;
      float v = ldf(&convo[(size_t)(row0 + st * 64 + s) * CONV_DIM + h * HD + pp]) *
                sDt[st * 64 + s];
      sH[pp * 64 + (((s >> 3) ^ (pp & 7)) * 8) + (s & 7)] = f2bu(v);
    }
    __syncthreads();
    if (wid >= st) {
#pragma unroll
      for (int sf = 0; sf < 4; ++sf) {
        f32x4 d[4] = {};
#pragma unroll
        for (int kc = 0; kc < 4; ++kc) {
          int srow = sf * 16 + sl;
          bf16x8 bfv = *reinterpret_cast<const bf16x8*>(
              &sB[srow * 128 + (((kc * 4 + hi) ^ (srow & 7)) * 8)]);
#pragma unroll
          for (int m = 0; m < 4; ++m) d[m] = MFMA16(cf[m][kc], bfv, d[m]);
        }
        int s_loc = sf * 16 + sl;
        int s_glob = st * 64 + s_loc;
        float acS = sAc[s_glob];
        bool diag = (st == wid);
#pragma unroll
        for (int m = 0; m < 4; ++m)
#pragma unroll
          for (int r = 0; r < 4; ++r) {
            int l_loc = m * 16 + hi * 4 + r;
            int l_glob = wid * 64 + l_loc;
            float e = __expf(sAc[l_glob] - acS);
            float v = d[m][r] * e;
            if (diag && s_glob > l_glob) v = 0.f;
            sWp[l_loc * 64 + (((s_loc >> 3) ^ (l_loc & 7)) * 8) + (s_loc & 7)] = f2bu(v);
          }
      }
    }
    __syncthreads();
    if (wid >= st) {
#pragma unroll
      for (int kc = 0; kc < 2; ++kc) {
        bf16x8 a[4], bb[4];
#pragma unroll
        for (int m = 0; m < 4; ++m) {
          int l = m * 16 + sl;
          a[m] = *reinterpret_cast<const bf16x8*>(
              &sWp[l * 64 + (((kc * 4 + hi) ^ (l & 7)) * 8)]);
        }
#pragma unroll
        for (int j = 0; j < 4; ++j) {
          int p = j * 16 + sl;
          bb[j] = *reinterpret_cast<const bf16x8*>(
              &sH[p * 64 + (((kc * 4 + hi) ^ (p & 7)) * 8)]);
        }
#pragma unroll
        for (int m = 0; m < 4; ++m)
#pragma unroll
          for (int j = 0; j < 4; ++j) acc[m][j] = MFMA16(a[m], bb[j], acc[m][j]);
      }
    }
  }

  __syncthreads();
  {
    size_t sinbase = ((size_t)(((b * NC + c) * NH + h) * HD)) * SSZ;
#pragma unroll
    for (int it = 0; it < 8; ++it) {
      int cid = tid + it * 256;
      int p = cid >> 5, q = cid & 31;
      float4 v = *reinterpret_cast<const float4*>(&cs[sinbase + (size_t)p * SSZ + q * 4]);
      uint2 val = make_uint2(pack2(v.x, v.y), pack2(v.z, v.w));
      *reinterpret_cast<uint2*>(&sB[p * 128 + ((q >> 1) ^ (p & 7)) * 8 + (q & 1) * 4]) = val;
    }
  }
  __syncthreads();
#pragma unroll
  for (int m = 0; m < 4; ++m) {
    float e = __expf(sAc[wid * 64 + m * 16 + sl]);
#pragma unroll
    for (int kc = 0; kc < 4; ++kc) {
      bf16x8 fv = cf[m][kc];
#pragma unroll
      for (int ei = 0; ei < 8; ++ei) {
        unsigned short us = (unsigned short)fv[ei];
        fv[ei] = (short)f2bu(bu2f(us) * e);
      }
      cf[m][kc] = fv;
    }
  }
#pragma unroll
  for (int kc = 0; kc < 4; ++kc) {
    bf16x8 bb[4];
#pragma unroll
    for (int j = 0; j < 4; ++j) {
      int p = j * 16 + sl;
      bb[j] = *reinterpret_cast<const bf16x8*>(
          &sB[p * 128 + (((kc * 4 + hi) ^ (p & 7)) * 8)]);
    }
#pragma unroll
    for (int m = 0; m < 4; ++m)
#pragma unroll
      for (int j = 0; j < 4; ++j) acc[m][j] = MFMA16(cf[m][kc], bb[j], acc[m][j]);
  }

  float Dh = Dp[h];
#pragma unroll
  for (int m = 0; m < 4; ++m)
#pragma unroll
    for (int j = 0; j < 4; ++j)
#pragma unroll
      for (int r = 0; r < 4; ++r) {
        int l_glob = wid * 64 + m * 16 + hi * 4 + r;
        size_t row = (size_t)(row0 + l_glob);
        int pg = j * 16 + sl;
        float hraw = ldf(&convo[row * CONV_DIM + h * HD + pg]);
        yb[row * INTER + h * HD + pg] = __float2bfloat16(acc[m][j][r] + Dh * hraw);
      }
}

// ---------------- gate SiLU + RMSNorm (in-place on yb) ----------------
__global__ __launch_bounds__(256) void norm_k(const bf16* __restrict__ proj,
                                              const float* __restrict__ nw,
                                              bf16* __restrict__ yb) {
  int row = blockIdx.x;
  int tid = threadIdx.x;
  float vals[16];
  float ss = 0.f;
#pragma unroll
  for (int i = 0; i < 16; i++) {
    int col = tid + i * 256;
    float gt = ldf(&proj[(size_t)row * PROJ_DIM + col]);
    float yf = ldf(&yb[(size_t)row * INTER + col]) * siluf(gt);
    vals[i] = yf;
    ss += yf * yf;
  }
#pragma unroll
  for (int off = 32; off > 0; off >>= 1) ss += __shfl_down(ss, off);
  __shared__ float red[4];
  if ((tid & 63) == 0) red[tid >> 6] = ss;
  __syncthreads();
  float tot = red[0] + red[1] + red[2] + red[3];
  float scale = rsqrtf(tot * (1.f / INTER) + 1e-6f);
#pragma unroll
  for (int i = 0; i < 16; i++) {
    int col = tid + i * 256;
    yb[(size_t)row * INTER + col] = __float2bfloat16(vals[i] * scale * nw[col]);
  }
}

extern "C" void kernel_launch(void* const* d_in, const int* in_sizes, int n_in,
                              void* d_out, int out_size, void* d_ws, size_t ws_size,
                              hipStream_t stream) {
  const float* x     = (const float*)d_in[0];
  const float* wproj = (const float*)d_in[1];
  const float* cw    = (const float*)d_in[2];
  const float* cb    = (const float*)d_in[3];
  const float* dtb   = (const float*)d_in[4];
  const float* alog  = (const float*)d_in[5];
  const float* Dp    = (const float*)d_in[6];
  const float* nw    = (const float*)d_in[7];
  const float* wout  = (const float*)d_in[8];
  float* out = (float*)d_out;
  char* ws = (char*)d_ws;

  // persistent layout (~195 MiB, proven safe)
  bf16*  proj  = (bf16*)(ws);                    // 84,410,368 B
  bf16*  convo = (bf16*)(ws + 84410368);         // 50,331,648 B
  bf16*  yb    = (bf16*)(ws + 134742016);        // 33,554,432 B
  float* dtp   = (float*)(ws + 168296448);       //  1,048,576 B
  float* acum  = (float*)(ws + 169345024);       //  1,048,576 B
  float* cs    = (float*)(ws + 170393600);       // 33,554,432 B
  // liveness-overlapped temporaries (no extra footprint):
  unsigned short* Wt1 = (unsigned short*)(ws + 84410368);   // in convo (dead until conv)
  unsigned short* xb  = (unsigned short*)(ws + 134742016);  // in yb (dead until chunk_out)
  unsigned short* Wt2 = (unsigned short*)(ws + 170393600);  // in cs (dead after chunk_out)

  cvt_bf16_k<<<dim3(2048), 256, 0, stream>>>(x, xb, ROWS * HIDDEN / 4);
  wT_k<<<dim3(PROJ_PAD / 64, HIDDEN / 64), 256, 0, stream>>>(wproj, Wt1, HIDDEN, PROJ_DIM);
  gemm_bf16<bf16><<<dim3(PROJ_PAD / 128, ROWS / 128), 256, 0, stream>>>(
      xb, Wt1, proj, ROWS, PROJ_DIM, HIDDEN);
  conv_silu_k<<<dim3(ROWS * CONV_DIM / 256), 256, 0, stream>>>(proj, cw, cb, convo);
  dt_k<<<dim3(ROWS * NH / 256), 256, 0, stream>>>(proj, dtb, dtp);
  acum_k<<<dim3(2 * NH * NC), 256, 0, stream>>>(dtp, alog, acum);
  chunk_states_k<<<dim3(2 * NC * NH), 256, 0, stream>>>(convo, dtp, acum, cs);
  chunk_rec_k<<<dim3(2 * NH * HD * SSZ / 256), 256, 0, stream>>>(acum, cs);
  chunk_out_mfma<<<dim3(2 * NC * NH), 256, 0, stream>>>(convo, dtp, acum, cs, Dp, yb);
  norm_k<<<dim3(ROWS), 256, 0, stream>>>(proj, nw, yb);
  wT_k<<<dim3(HIDDEN / 64, INTER / 64), 256, 0, stream>>>(wout, Wt2, INTER, HIDDEN);
  gemm_bf16<float><<<dim3(HIDDEN / 128, ROWS / 128), 256, 0, stream>>>(
      (const unsigned short*)yb, Wt2, out, ROWS, HIDDEN, INTER);
}

// Round 6
// 567.914 us; speedup vs baseline: 14.6810x; 1.2290x over previous
//
#include <hip/hip_runtime.h>
#include <hip/hip_bf16.h>

// Mamba2 mixer — bf16 MFMA GEMMs (XCD-swizzled) + MFMA chunk_out/chunk_states.
// B=2 S=2048 HID=2048 INTER=4096 NH=64 HD=64 NG=8 SS=128 CK=4 CH=256 NC=8

#define S_LEN 2048
#define HIDDEN 2048
#define INTER 4096
#define NH 64
#define HD 64
#define NG 8
#define SSZ 128
#define CONV_DIM 6144
#define PROJ_DIM 10304
#define PROJ_PAD 10368     // 81*128
#define NC 8
#define CHK 256
#define ROWS 4096          // B*S
#define DT_OFF 10240       // INTER + CONV_DIM
#define B_OFF 4096         // B section inside conv block
#define C_OFF 5120         // C section inside conv block

typedef __hip_bfloat16 bf16;
typedef __attribute__((ext_vector_type(8))) short bf16x8;
typedef __attribute__((ext_vector_type(4))) float f32x4;
#define MFMA16(a, b, c) __builtin_amdgcn_mfma_f32_16x16x32_bf16(a, b, c, 0, 0, 0)

union U16x8 { uint4 u; bf16x8 v; };

__device__ __forceinline__ float siluf(float x) { return x / (1.f + __expf(-x)); }
__device__ __forceinline__ float ldf(const float* p) { return *p; }
__device__ __forceinline__ float ldf(const bf16* p) { return __bfloat162float(*p); }
__device__ __forceinline__ unsigned short f2bu(float x) {
  bf16 h = __float2bfloat16(x);
  return __builtin_bit_cast(unsigned short, h);
}
__device__ __forceinline__ float bu2f(unsigned short u) {
  return __uint_as_float(((unsigned)u) << 16);
}
__device__ __forceinline__ unsigned pack2(float lo, float hi) {
  return ((unsigned)f2bu(hi) << 16) | f2bu(lo);
}
// async global->LDS, 16B per lane; LDS dst wave-uniform (HW adds lane*16)
__device__ __forceinline__ void gload16(const void* g, void* l) {
  __builtin_amdgcn_global_load_lds((const __attribute__((address_space(1))) unsigned*)g,
                                   (__attribute__((address_space(3))) unsigned*)l, 16, 0, 0);
}

// ---------------- fp32 -> bf16 bulk convert ----------------
__global__ __launch_bounds__(256) void cvt_bf16_k(const float* __restrict__ x,
                                                  unsigned short* __restrict__ o, int n4) {
  int idx = blockIdx.x * 256 + threadIdx.x;
  int stride = gridDim.x * 256;
  for (int i = idx; i < n4; i += stride) {
    float4 v = reinterpret_cast<const float4*>(x)[i];
    uint2 u = make_uint2(pack2(v.x, v.y), pack2(v.z, v.w));
    reinterpret_cast<uint2*>(o)[i] = u;
  }
}

// ------------- weight transpose+convert: W[K][N] f32 -> Wt[NP][K] bf16 ----------
__global__ __launch_bounds__(256) void wT_k(const float* __restrict__ W,
                                            unsigned short* __restrict__ Wt,
                                            int K, int N) {
  __shared__ unsigned short t[64][72];
  int n0 = blockIdx.x * 64, k0 = blockIdx.y * 64;
  int tid = threadIdx.x;
#pragma unroll
  for (int i = 0; i < 16; ++i) {
    int idx = tid + i * 256;
    int kr = idx >> 6, nc = idx & 63;
    float v = (n0 + nc < N) ? W[(size_t)(k0 + kr) * N + n0 + nc] : 0.f;
    t[kr][nc] = f2bu(v);
  }
  __syncthreads();
#pragma unroll
  for (int i = 0; i < 16; ++i) {
    int idx = tid + i * 256;
    int nr = idx >> 6, kc = idx & 63;
    Wt[(size_t)(n0 + nr) * K + k0 + kc] = t[kc][nr];
  }
}

// ================= bf16 MFMA GEMM: C[M,N] = A[M,K] @ Wt[N,K]^T ==============
// 128xBN tile, BK=64, 256 threads (4 waves 2x2). global_load_lds staging with
// pre-swizzled source (slot ^= row&7); XCD-aware bijective block swizzle.
template <int BN, typename TC>
__global__ __launch_bounds__(256) void gemm_bf16(const unsigned short* __restrict__ A,
                                                 const unsigned short* __restrict__ Bt,
                                                 TC* __restrict__ C,
                                                 int M, int N, int K) {
  __shared__ __align__(16) unsigned short sA[128 * 64];
  __shared__ __align__(16) unsigned short sB[BN * 64];
  const int tid = threadIdx.x;
  const int lane = tid & 63, hi = lane >> 4, sl = lane & 15;
  const int wid = tid >> 6, wm = wid >> 1, wn = wid & 1;
  // XCD swizzle (nwg % 8 == 0 for all launches here -> bijective)
  const int gx = gridDim.x;
  int lin = blockIdx.y * gx + blockIdx.x;
  int cpx = (gx * gridDim.y) >> 3;
  int swz = (lin & 7) * cpx + (lin >> 3);
  const int m0 = (swz / gx) * 128;
  const int n0 = (swz % gx) * BN;
  const int lrow = lane >> 3;   // row within 8-row chunk
  const int lslot = lane & 7;   // 16B slot within 128B row
  constexpr int NCH = 16 + BN / 8;   // 8-row chunks total (A=16, B=BN/8)
  constexpr int PER = NCH / 4;       // chunks per wave
  constexpr int FN = BN / 32;        // B fragments per wave

  f32x4 acc[4][FN] = {};
  for (int kt = 0; kt < K; kt += 64) {
    __syncthreads();  // protect LDS from prev-iter readers
#pragma unroll
    for (int i = 0; i < PER; ++i) {
      int ch = wid * PER + i;
      if (ch < 16) {
        int r = ch * 8 + lrow;
        int g = lslot ^ (r & 7);
        gload16(&A[(size_t)(m0 + r) * K + kt + g * 8], &sA[ch * 512]);
      } else {
        int r = (ch - 16) * 8 + lrow;
        int g = lslot ^ (r & 7);
        gload16(&Bt[(size_t)(n0 + r) * K + kt + g * 8], &sB[(ch - 16) * 512]);
      }
    }
    __syncthreads();  // drains vmcnt(0) -> tiles resident
#pragma unroll
    for (int su = 0; su < 2; ++su) {
      bf16x8 af[4], bfr[FN];
#pragma unroll
      for (int m = 0; m < 4; ++m) {
        int r = wm * 64 + m * 16 + sl;
        af[m] = *reinterpret_cast<const bf16x8*>(
            &sA[r * 64 + (((su * 4 + hi) ^ (r & 7)) * 8)]);
      }
#pragma unroll
      for (int j = 0; j < FN; ++j) {
        int r = wn * (BN / 2) + j * 16 + sl;
        bfr[j] = *reinterpret_cast<const bf16x8*>(
            &sB[r * 64 + (((su * 4 + hi) ^ (r & 7)) * 8)]);
      }
#pragma unroll
      for (int m = 0; m < 4; ++m)
#pragma unroll
        for (int j = 0; j < FN; ++j)
          acc[m][j] = MFMA16(af[m], bfr[j], acc[m][j]);
    }
  }
#pragma unroll
  for (int m = 0; m < 4; ++m)
#pragma unroll
    for (int j = 0; j < FN; ++j) {
      int col = n0 + wn * (BN / 2) + j * 16 + sl;
      if (col < N) {
#pragma unroll
        for (int r = 0; r < 4; ++r) {
          int row = m0 + wm * 64 + m * 16 + hi * 4 + r;
          if constexpr (sizeof(TC) == 2)
            C[(size_t)row * N + col] = __float2bfloat16(acc[m][j][r]);
          else
            C[(size_t)row * N + col] = acc[m][j][r];
        }
      }
    }
}

// ------------- depthwise conv (SAME, k=4, pad_lo=1) + SiLU, bf16x8 ----------
__global__ __launch_bounds__(256) void conv_silu_k(const bf16* __restrict__ proj,
                                                   const float* __restrict__ cw,
                                                   const float* __restrict__ cb,
                                                   bf16* __restrict__ convo) {
  int idx = blockIdx.x * 256 + threadIdx.x;  // < ROWS*CONV_DIM/8
  int ci = idx % (CONV_DIM / 8);
  int row = idx / (CONV_DIM / 8);
  int c8 = ci * 8;
  int t = row & (S_LEN - 1);
  int b = row >> 11;
  float acc[8];
  {
    float4 b0 = *reinterpret_cast<const float4*>(&cb[c8]);
    float4 b1 = *reinterpret_cast<const float4*>(&cb[c8 + 4]);
    acc[0] = b0.x; acc[1] = b0.y; acc[2] = b0.z; acc[3] = b0.w;
    acc[4] = b1.x; acc[5] = b1.y; acc[6] = b1.z; acc[7] = b1.w;
  }
#pragma unroll
  for (int w = 0; w < 4; w++) {
    int tt = t + w - 1;
    if (tt >= 0 && tt < S_LEN) {
      U16x8 u;
      u.u = *reinterpret_cast<const uint4*>(
          &proj[(size_t)(b * S_LEN + tt) * PROJ_DIM + INTER + c8]);
      float4 w0 = *reinterpret_cast<const float4*>(&cw[w * CONV_DIM + c8]);
      float4 w1 = *reinterpret_cast<const float4*>(&cw[w * CONV_DIM + c8 + 4]);
      acc[0] += w0.x * bu2f((unsigned short)u.v[0]);
      acc[1] += w0.y * bu2f((unsigned short)u.v[1]);
      acc[2] += w0.z * bu2f((unsigned short)u.v[2]);
      acc[3] += w0.w * bu2f((unsigned short)u.v[3]);
      acc[4] += w1.x * bu2f((unsigned short)u.v[4]);
      acc[5] += w1.y * bu2f((unsigned short)u.v[5]);
      acc[6] += w1.z * bu2f((unsigned short)u.v[6]);
      acc[7] += w1.w * bu2f((unsigned short)u.v[7]);
    }
  }
  uint4 o;
  o.x = pack2(siluf(acc[0]), siluf(acc[1]));
  o.y = pack2(siluf(acc[2]), siluf(acc[3]));
  o.z = pack2(siluf(acc[4]), siluf(acc[5]));
  o.w = pack2(siluf(acc[6]), siluf(acc[7]));
  *reinterpret_cast<uint4*>(&convo[(size_t)row * CONV_DIM + c8]) = o;
}

// ---------------- dt = softplus(dt_raw + dt_bias) ----------------
__global__ __launch_bounds__(256) void dt_k(const bf16* __restrict__ proj,
                                            const float* __restrict__ dtb,
                                            float* __restrict__ dtp) {
  int idx = blockIdx.x * 256 + threadIdx.x;
  int h = idx & 63;
  int row = idx >> 6;
  float x = ldf(&proj[(size_t)row * PROJ_DIM + DT_OFF + h]) + dtb[h];
  dtp[idx] = (x > 20.f) ? x : log1pf(__expf(x));
}

// ---------------- per-chunk cumsum of A[h]*dt ----------------
__global__ __launch_bounds__(256) void acum_k(const float* __restrict__ dtp,
                                              const float* __restrict__ alog,
                                              float* __restrict__ acum) {
  __shared__ float buf[2][CHK];
  int blk = blockIdx.x;
  int c = blk & 7;
  int h = (blk >> 3) & 63;
  int b = blk >> 9;
  int tid = threadIdx.x;
  int row0 = b * S_LEN + c * CHK;
  float a = -__expf(alog[h]);
  buf[0][tid] = a * dtp[(size_t)(row0 + tid) * NH + h];
  __syncthreads();
  int cur = 0;
#pragma unroll
  for (int off = 1; off < 256; off <<= 1) {
    float nv = buf[cur][tid];
    if (tid >= off) nv += buf[cur][tid - off];
    buf[cur ^ 1][tid] = nv;
    cur ^= 1;
    __syncthreads();
  }
  acum[(size_t)blk * CHK + tid] = buf[cur][tid];
}

// ======== per-chunk states via MFMA: cs[p,n] = sum_t hsdt[t,p]*Bdecay[t,n] ====
// grid 1024 = (b,c,h); 4 waves 2x2 over 64p x 128n; K=256 in 4 tiles of 64.
__global__ __launch_bounds__(256) void chunk_states_mfma(const bf16* __restrict__ convo,
                                                         const float* __restrict__ dtp,
                                                         const float* __restrict__ acum,
                                                         float* __restrict__ cs) {
  __shared__ float sAc[CHK];
  __shared__ float sDtf[CHK];
  __shared__ float sEx[64];
  __shared__ __align__(16) unsigned short sHT[64 * 64];    // [p][t] swizzled
  __shared__ __align__(16) unsigned short sBd[128 * 64];   // [n][t] swizzled
  const int tid = threadIdx.x;
  const int lane = tid & 63, hi = lane >> 4, sl = lane & 15;
  const int wid = tid >> 6, wm = wid >> 1, wn = wid & 1;
  const int blk = blockIdx.x;
  const int h = blk & 63, bc = blk >> 6, c = bc & 7, b = bc >> 3, g = h >> 3;
  const int row0 = b * S_LEN + c * CHK;
  sAc[tid] = acum[((size_t)((b * NH + h) * NC + c)) * CHK + tid];
  sDtf[tid] = dtp[(size_t)(row0 + tid) * NH + h];
  f32x4 acc[2][4] = {};
  for (int ts = 0; ts < 4; ++ts) {
    __syncthreads();                    // buffers free; sAc/sDtf ready at ts=0
    if (tid < 64) sEx[tid] = __expf(sAc[CHK - 1] - sAc[ts * 64 + tid]);
    __syncthreads();
    // stage sHT [p][t]: swizzle G(p) = (p&7)^((p>>3)&7) (conflict-free writes)
#pragma unroll
    for (int it = 0; it < 2; ++it) {
      int cid = tid + it * 256;         // 0..511
      int t = cid >> 3, p8 = (cid & 7) * 8;
      U16x8 u;
      u.u = *reinterpret_cast<const uint4*>(
          &convo[(size_t)(row0 + ts * 64 + t) * CONV_DIM + h * HD + p8]);
      float dtv = sDtf[ts * 64 + t];
#pragma unroll
      for (int e = 0; e < 8; ++e) {
        int p = p8 + e;
        int G = (p & 7) ^ ((p >> 3) & 7);
        sHT[p * 64 + (((t >> 3) ^ G) * 8) + (t & 7)] =
            f2bu(bu2f((unsigned short)u.v[e]) * dtv);
      }
    }
    // stage sBd [n][t]
#pragma unroll
    for (int it = 0; it < 4; ++it) {
      int cid = tid + it * 256;         // 0..1023
      int t = cid >> 4, n8 = (cid & 15) * 8;
      U16x8 u;
      u.u = *reinterpret_cast<const uint4*>(
          &convo[(size_t)(row0 + ts * 64 + t) * CONV_DIM + B_OFF + g * SSZ + n8]);
      float ex = sEx[t];
#pragma unroll
      for (int e = 0; e < 8; ++e) {
        int n = n8 + e;
        int G = (n & 7) ^ ((n >> 3) & 7);
        sBd[n * 64 + (((t >> 3) ^ G) * 8) + (t & 7)] =
            f2bu(bu2f((unsigned short)u.v[e]) * ex);
      }
    }
    __syncthreads();
#pragma unroll
    for (int kc = 0; kc < 2; ++kc) {
      bf16x8 a[2], bb[4];
#pragma unroll
      for (int m = 0; m < 2; ++m) {
        int p = wm * 32 + m * 16 + sl;
        int G = (p & 7) ^ ((p >> 3) & 7);
        a[m] = *reinterpret_cast<const bf16x8*>(
            &sHT[p * 64 + (((kc * 4 + hi) ^ G) * 8)]);
      }
#pragma unroll
      for (int j = 0; j < 4; ++j) {
        int n = wn * 64 + j * 16 + sl;
        int G = (n & 7) ^ ((n >> 3) & 7);
        bb[j] = *reinterpret_cast<const bf16x8*>(
            &sBd[n * 64 + (((kc * 4 + hi) ^ G) * 8)]);
      }
#pragma unroll
      for (int m = 0; m < 2; ++m)
#pragma unroll
        for (int j = 0; j < 4; ++j) acc[m][j] = MFMA16(a[m], bb[j], acc[m][j]);
    }
  }
  size_t base = (size_t)blk * HD * SSZ;  // [b][c][h][p][n]
#pragma unroll
  for (int m = 0; m < 2; ++m)
#pragma unroll
    for (int j = 0; j < 4; ++j)
#pragma unroll
      for (int r = 0; r < 4; ++r) {
        int p = wm * 32 + m * 16 + hi * 4 + r;
        int n = wn * 64 + j * 16 + sl;
        cs[base + (size_t)p * SSZ + n] = acc[m][j][r];
      }
}

// ---------------- inter-chunk recurrence (in-place) ----------------
__global__ __launch_bounds__(256) void chunk_rec_k(const float* __restrict__ acum,
                                                   float* __restrict__ cs) {
  int idx = blockIdx.x * 256 + threadIdx.x;
  int n = idx & 127;
  int p = (idx >> 7) & 63;
  int h = (idx >> 13) & 63;
  int b = idx >> 19;
  float run = 0.f;
#pragma unroll
  for (int c = 0; c < NC; c++) {
    size_t off = ((size_t)(((b * NC + c) * NH + h) * HD + p)) * SSZ + n;
    float csv = cs[off];
    float al = acum[((size_t)((b * NH + h) * NC + c)) * CHK + (CHK - 1)];
    cs[off] = run;
    run = run * __expf(al) + csv;
  }
}

// ================= chunk output via MFMA (flash-style) =======================
__global__ __launch_bounds__(256) void chunk_out_mfma(const bf16* __restrict__ convo,
                                                      const float* __restrict__ dtp,
                                                      const float* __restrict__ acum,
                                                      const float* __restrict__ cs,
                                                      const float* __restrict__ Dp,
                                                      bf16* __restrict__ yb) {
  __shared__ float sAc[CHK];
  __shared__ float sDt[CHK];
  __shared__ __align__(16) unsigned short sB[64 * 128];
  __shared__ __align__(16) unsigned short sH[64 * 64];
  __shared__ __align__(16) unsigned short sW[4 * 64 * 64];
  const int tid = threadIdx.x;
  const int lane = tid & 63, hi = lane >> 4, sl = lane & 15;
  const int wid = tid >> 6;
  const int blk = blockIdx.x;
  const int h = blk & 63;
  const int bc = blk >> 6;
  const int c = bc & 7;
  const int b = bc >> 3;
  const int g = h >> 3;
  const int row0 = b * S_LEN + c * CHK;
  unsigned short* sWp = &sW[wid * 4096];

  sAc[tid] = acum[((size_t)((b * NH + h) * NC + c)) * CHK + tid];
  sDt[tid] = dtp[(size_t)(row0 + tid) * NH + h];

  bf16x8 cf[4][4];
#pragma unroll
  for (int m = 0; m < 4; ++m)
#pragma unroll
    for (int kc = 0; kc < 4; ++kc) {
      int l = wid * 64 + m * 16 + sl;
      U16x8 u;
      u.u = *reinterpret_cast<const uint4*>(
          &convo[(size_t)(row0 + l) * CONV_DIM + C_OFF + g * SSZ + kc * 32 + hi * 8]);
      cf[m][kc] = u.v;
    }

  f32x4 acc[4][4] = {};

  for (int st = 0; st < 4; ++st) {
    __syncthreads();
#pragma unroll
    for (int it = 0; it < 4; ++it) {
      int cid = tid + it * 256;
      int s = cid >> 4, gr = cid & 15;
      const uint4* p = reinterpret_cast<const uint4*>(
          &convo[(size_t)(row0 + st * 64 + s) * CONV_DIM + B_OFF + g * SSZ + gr * 8]);
      *reinterpret_cast<uint4*>(&sB[s * 128 + (gr ^ (s & 7)) * 8]) = *p;
    }
#pragma unroll
    for (int it = 0; it < 16; ++it) {
      int cid = tid + it * 256;
      int s = cid >> 6, pp = cid & 63;
      float v = ldf(&convo[(size_t)(row0 + st * 64 + s) * CONV_DIM + h * HD + pp]) *
                sDt[st * 64 + s];
      sH[pp * 64 + (((s >> 3) ^ (pp & 7)) * 8) + (s & 7)] = f2bu(v);
    }
    __syncthreads();
    if (wid >= st) {
#pragma unroll
      for (int sf = 0; sf < 4; ++sf) {
        f32x4 d[4] = {};
#pragma unroll
        for (int kc = 0; kc < 4; ++kc) {
          int srow = sf * 16 + sl;
          bf16x8 bfv = *reinterpret_cast<const bf16x8*>(
              &sB[srow * 128 + (((kc * 4 + hi) ^ (srow & 7)) * 8)]);
#pragma unroll
          for (int m = 0; m < 4; ++m) d[m] = MFMA16(cf[m][kc], bfv, d[m]);
        }
        int s_loc = sf * 16 + sl;
        int s_glob = st * 64 + s_loc;
        float acS = sAc[s_glob];
        bool diag = (st == wid);
#pragma unroll
        for (int m = 0; m < 4; ++m)
#pragma unroll
          for (int r = 0; r < 4; ++r) {
            int l_loc = m * 16 + hi * 4 + r;
            int l_glob = wid * 64 + l_loc;
            float e = __expf(sAc[l_glob] - acS);
            float v = d[m][r] * e;
            if (diag && s_glob > l_glob) v = 0.f;
            sWp[l_loc * 64 + (((s_loc >> 3) ^ (l_loc & 7)) * 8) + (s_loc & 7)] = f2bu(v);
          }
      }
    }
    __syncthreads();
    if (wid >= st) {
#pragma unroll
      for (int kc = 0; kc < 2; ++kc) {
        bf16x8 a[4], bb[4];
#pragma unroll
        for (int m = 0; m < 4; ++m) {
          int l = m * 16 + sl;
          a[m] = *reinterpret_cast<const bf16x8*>(
              &sWp[l * 64 + (((kc * 4 + hi) ^ (l & 7)) * 8)]);
        }
#pragma unroll
        for (int j = 0; j < 4; ++j) {
          int p = j * 16 + sl;
          bb[j] = *reinterpret_cast<const bf16x8*>(
              &sH[p * 64 + (((kc * 4 + hi) ^ (p & 7)) * 8)]);
        }
#pragma unroll
        for (int m = 0; m < 4; ++m)
#pragma unroll
          for (int j = 0; j < 4; ++j) acc[m][j] = MFMA16(a[m], bb[j], acc[m][j]);
      }
    }
  }

  __syncthreads();
  {
    size_t sinbase = ((size_t)(((b * NC + c) * NH + h) * HD)) * SSZ;
#pragma unroll
    for (int it = 0; it < 8; ++it) {
      int cid = tid + it * 256;
      int p = cid >> 5, q = cid & 31;
      float4 v = *reinterpret_cast<const float4*>(&cs[sinbase + (size_t)p * SSZ + q * 4]);
      uint2 val = make_uint2(pack2(v.x, v.y), pack2(v.z, v.w));
      *reinterpret_cast<uint2*>(&sB[p * 128 + ((q >> 1) ^ (p & 7)) * 8 + (q & 1) * 4]) = val;
    }
  }
  __syncthreads();
#pragma unroll
  for (int m = 0; m < 4; ++m) {
    float e = __expf(sAc[wid * 64 + m * 16 + sl]);
#pragma unroll
    for (int kc = 0; kc < 4; ++kc) {
      bf16x8 fv = cf[m][kc];
#pragma unroll
      for (int ei = 0; ei < 8; ++ei) {
        unsigned short us = (unsigned short)fv[ei];
        fv[ei] = (short)f2bu(bu2f(us) * e);
      }
      cf[m][kc] = fv;
    }
  }
#pragma unroll
  for (int kc = 0; kc < 4; ++kc) {
    bf16x8 bb[4];
#pragma unroll
    for (int j = 0; j < 4; ++j) {
      int p = j * 16 + sl;
      bb[j] = *reinterpret_cast<const bf16x8*>(
          &sB[p * 128 + (((kc * 4 + hi) ^ (p & 7)) * 8)]);
    }
#pragma unroll
    for (int m = 0; m < 4; ++m)
#pragma unroll
      for (int j = 0; j < 4; ++j) acc[m][j] = MFMA16(cf[m][kc], bb[j], acc[m][j]);
  }

  float Dh = Dp[h];
#pragma unroll
  for (int m = 0; m < 4; ++m)
#pragma unroll
    for (int j = 0; j < 4; ++j)
#pragma unroll
      for (int r = 0; r < 4; ++r) {
        int l_glob = wid * 64 + m * 16 + hi * 4 + r;
        size_t row = (size_t)(row0 + l_glob);
        int pg = j * 16 + sl;
        float hraw = ldf(&convo[row * CONV_DIM + h * HD + pg]);
        yb[row * INTER + h * HD + pg] = __float2bfloat16(acc[m][j][r] + Dh * hraw);
      }
}

// ------------- gate SiLU + RMSNorm (in-place on yb), bf16x8 -------------
__global__ __launch_bounds__(256) void norm_k(const bf16* __restrict__ proj,
                                              const float* __restrict__ nw,
                                              bf16* __restrict__ yb) {
  int row = blockIdx.x;
  int tid = threadIdx.x;
  float vals[16];
  float ss = 0.f;
#pragma unroll
  for (int half = 0; half < 2; half++) {
    int colb = tid * 8 + half * 2048;
    U16x8 gy, gg;
    gy.u = *reinterpret_cast<const uint4*>(&yb[(size_t)row * INTER + colb]);
    gg.u = *reinterpret_cast<const uint4*>(&proj[(size_t)row * PROJ_DIM + colb]);
#pragma unroll
    for (int e = 0; e < 8; e++) {
      float yf = bu2f((unsigned short)gy.v[e]) * siluf(bu2f((unsigned short)gg.v[e]));
      vals[half * 8 + e] = yf;
      ss += yf * yf;
    }
  }
#pragma unroll
  for (int off = 32; off > 0; off >>= 1) ss += __shfl_down(ss, off);
  __shared__ float red[4];
  if ((tid & 63) == 0) red[tid >> 6] = ss;
  __syncthreads();
  float tot = red[0] + red[1] + red[2] + red[3];
  float scale = rsqrtf(tot * (1.f / INTER) + 1e-6f);
#pragma unroll
  for (int half = 0; half < 2; half++) {
    int colb = tid * 8 + half * 2048;
    float4 w0 = *reinterpret_cast<const float4*>(&nw[colb]);
    float4 w1 = *reinterpret_cast<const float4*>(&nw[colb + 4]);
    float s0 = vals[half * 8 + 0] * scale * w0.x, s1 = vals[half * 8 + 1] * scale * w0.y;
    float s2 = vals[half * 8 + 2] * scale * w0.z, s3 = vals[half * 8 + 3] * scale * w0.w;
    float s4 = vals[half * 8 + 4] * scale * w1.x, s5 = vals[half * 8 + 5] * scale * w1.y;
    float s6 = vals[half * 8 + 6] * scale * w1.z, s7 = vals[half * 8 + 7] * scale * w1.w;
    uint4 o = make_uint4(pack2(s0, s1), pack2(s2, s3), pack2(s4, s5), pack2(s6, s7));
    *reinterpret_cast<uint4*>(&yb[(size_t)row * INTER + colb]) = o;
  }
}

extern "C" void kernel_launch(void* const* d_in, const int* in_sizes, int n_in,
                              void* d_out, int out_size, void* d_ws, size_t ws_size,
                              hipStream_t stream) {
  const float* x     = (const float*)d_in[0];
  const float* wproj = (const float*)d_in[1];
  const float* cw    = (const float*)d_in[2];
  const float* cb    = (const float*)d_in[3];
  const float* dtb   = (const float*)d_in[4];
  const float* alog  = (const float*)d_in[5];
  const float* Dp    = (const float*)d_in[6];
  const float* nw    = (const float*)d_in[7];
  const float* wout  = (const float*)d_in[8];
  float* out = (float*)d_out;
  char* ws = (char*)d_ws;

  // persistent layout (~195 MiB, proven safe)
  bf16*  proj  = (bf16*)(ws);                    // 84,410,368 B
  bf16*  convo = (bf16*)(ws + 84410368);         // 50,331,648 B
  bf16*  yb    = (bf16*)(ws + 134742016);        // 33,554,432 B
  float* dtp   = (float*)(ws + 168296448);       //  1,048,576 B
  float* acum  = (float*)(ws + 169345024);       //  1,048,576 B
  float* cs    = (float*)(ws + 170393600);       // 33,554,432 B
  // liveness-overlapped temporaries (no extra footprint):
  unsigned short* Wt1 = (unsigned short*)(ws + 84410368);   // in convo (dead until conv)
  unsigned short* xb  = (unsigned short*)(ws + 134742016);  // in yb (dead until chunk_out)
  unsigned short* Wt2 = (unsigned short*)(ws + 170393600);  // in cs (dead after chunk_out)

  cvt_bf16_k<<<dim3(2048), 256, 0, stream>>>(x, xb, ROWS * HIDDEN / 4);
  wT_k<<<dim3(PROJ_PAD / 64, HIDDEN / 64), 256, 0, stream>>>(wproj, Wt1, HIDDEN, PROJ_DIM);
  gemm_bf16<128, bf16><<<dim3(PROJ_PAD / 128, ROWS / 128), 256, 0, stream>>>(
      xb, Wt1, proj, ROWS, PROJ_DIM, HIDDEN);
  conv_silu_k<<<dim3(ROWS * CONV_DIM / 8 / 256), 256, 0, stream>>>(proj, cw, cb, convo);
  dt_k<<<dim3(ROWS * NH / 256), 256, 0, stream>>>(proj, dtb, dtp);
  acum_k<<<dim3(2 * NH * NC), 256, 0, stream>>>(dtp, alog, acum);
  chunk_states_mfma<<<dim3(2 * NC * NH), 256, 0, stream>>>(convo, dtp, acum, cs);
  chunk_rec_k<<<dim3(2 * NH * HD * SSZ / 256), 256, 0, stream>>>(acum, cs);
  chunk_out_mfma<<<dim3(2 * NC * NH), 256, 0, stream>>>(convo, dtp, acum, cs, Dp, yb);
  norm_k<<<dim3(ROWS), 256, 0, stream>>>(proj, nw, yb);
  wT_k<<<dim3(HIDDEN / 64, INTER / 64), 256, 0, stream>>>(wout, Wt2, INTER, HIDDEN);
  gemm_bf16<64, float><<<dim3(HIDDEN / 64, ROWS / 128), 256, 0, stream>>>(
      (const unsigned short*)yb, Wt2, out, ROWS, HIDDEN, INTER);
}

// Round 7
// 514.993 us; speedup vs baseline: 16.1896x; 1.1028x over previous
//
#include <hip/hip_runtime.h>
#include <hip/hip_bf16.h>

// Mamba2 mixer — 256²/8-phase MFMA GEMM-1 (ring-9 LDS, counted vmcnt),
// proven 128-tile GEMM-2, MFMA chunk_out/chunk_states.
// B=2 S=2048 HID=2048 INTER=4096 NH=64 HD=64 NG=8 SS=128 CK=4 CH=256 NC=8

#define S_LEN 2048
#define HIDDEN 2048
#define INTER 4096
#define NH 64
#define HD 64
#define NG 8
#define SSZ 128
#define CONV_DIM 6144
#define PROJ_DIM 10304
#define PROJ_PAD 10496     // 41*256
#define NC 8
#define CHK 256
#define ROWS 4096          // B*S
#define DT_OFF 10240       // INTER + CONV_DIM
#define B_OFF 4096         // B section inside conv block
#define C_OFF 5120         // C section inside conv block

typedef __hip_bfloat16 bf16;
typedef __attribute__((ext_vector_type(8))) short bf16x8;
typedef __attribute__((ext_vector_type(4))) float f32x4;
#define MFMA16(a, b, c) __builtin_amdgcn_mfma_f32_16x16x32_bf16(a, b, c, 0, 0, 0)

union U16x8 { uint4 u; bf16x8 v; };

__device__ __forceinline__ float siluf(float x) { return x / (1.f + __expf(-x)); }
__device__ __forceinline__ float ldf(const float* p) { return *p; }
__device__ __forceinline__ float ldf(const bf16* p) { return __bfloat162float(*p); }
__device__ __forceinline__ unsigned short f2bu(float x) {
  bf16 h = __float2bfloat16(x);
  return __builtin_bit_cast(unsigned short, h);
}
__device__ __forceinline__ float bu2f(unsigned short u) {
  return __uint_as_float(((unsigned)u) << 16);
}
__device__ __forceinline__ unsigned pack2(float lo, float hi) {
  return ((unsigned)f2bu(hi) << 16) | f2bu(lo);
}
// async global->LDS, 16B per lane; LDS dst wave-uniform (HW adds lane*16)
__device__ __forceinline__ void gload16(const void* g, void* l) {
  __builtin_amdgcn_global_load_lds((const __attribute__((address_space(1))) unsigned*)g,
                                   (__attribute__((address_space(3))) unsigned*)l, 16, 0, 0);
}

// ---------------- fp32 -> bf16 bulk convert ----------------
__global__ __launch_bounds__(256) void cvt_bf16_k(const float* __restrict__ x,
                                                  unsigned short* __restrict__ o, int n4) {
  int idx = blockIdx.x * 256 + threadIdx.x;
  int stride = gridDim.x * 256;
  for (int i = idx; i < n4; i += stride) {
    float4 v = reinterpret_cast<const float4*>(x)[i];
    uint2 u = make_uint2(pack2(v.x, v.y), pack2(v.z, v.w));
    reinterpret_cast<uint2*>(o)[i] = u;
  }
}

// ------------- weight transpose+convert: W[K][N] f32 -> Wt[NP][K] bf16 ----------
__global__ __launch_bounds__(256) void wT_k(const float* __restrict__ W,
                                            unsigned short* __restrict__ Wt,
                                            int K, int N) {
  __shared__ unsigned short t[64][72];
  int n0 = blockIdx.x * 64, k0 = blockIdx.y * 64;
  int tid = threadIdx.x;
#pragma unroll
  for (int i = 0; i < 16; ++i) {
    int idx = tid + i * 256;
    int kr = idx >> 6, nc = idx & 63;
    float v = (n0 + nc < N) ? W[(size_t)(k0 + kr) * N + n0 + nc] : 0.f;
    t[kr][nc] = f2bu(v);
  }
  __syncthreads();
#pragma unroll
  for (int i = 0; i < 16; ++i) {
    int idx = tid + i * 256;
    int nr = idx >> 6, kc = idx & 63;
    Wt[(size_t)(n0 + nr) * K + k0 + kc] = t[kc][nr];
  }
}

// =========================== 256² / 8-phase GEMM ============================
// C[M,N] = A[M,K] @ Wt[N,K]^T. 512 thr (8 waves 2x4), BK=64.
// LDS ring of 9 half-tiles (16KB each = 128 rows x 64 k), slot = half % 9.
// Tile t halves: 4t+0 A[0:128), 4t+1 A[128:256), 4t+2 B[0:128), 4t+3 B[128:256).
// While computing tile t, stage halves 4t+5..4t+8 (one per phase).
// Entry of tile t: vmcnt(2) (only half 4t+4's 2 loads may be in flight) + barrier.
__device__ __forceinline__ int mod9(int x) { return x >= 9 ? x - 9 : x; }

__device__ __forceinline__ void stage_half(const unsigned short* __restrict__ A,
                                           const unsigned short* __restrict__ Bt,
                                           unsigned short* lds9, int hj, int slot,
                                           int m0, int n0, int K, int hmax,
                                           int tid, int wid) {
  if (hj >= hmax) return;
  const int t = hj >> 2, i = hj & 3;
  const unsigned short* src = (i < 2) ? A : Bt;
  const int br = ((i < 2) ? m0 : n0) + (i & 1) * 128;
  const int g = (tid & 7) ^ ((tid >> 3) & 7);   // inverse-swizzled source granule
#pragma unroll
  for (int r = 0; r < 2; ++r) {
    int row = r * 64 + (tid >> 3);
    gload16(&src[(size_t)(br + row) * K + t * 64 + g * 8],
            &lds9[slot * 8192 + r * 4096 + wid * 512]);
  }
}

template <typename TC>
__global__ __launch_bounds__(512, 2) void gemm_8ph(const unsigned short* __restrict__ A,
                                                   const unsigned short* __restrict__ Bt,
                                                   TC* __restrict__ C,
                                                   int M, int N, int K) {
  extern __shared__ unsigned short lds9[];
  const int tid = threadIdx.x;
  const int lane = tid & 63, hi = lane >> 4, sl = lane & 15;
  const int wid = tid >> 6;
  const int wm = wid >> 2, wn = wid & 3;
  const int gx = gridDim.x;
  int lin = blockIdx.y * gx + blockIdx.x;
  int cpx = (gx * gridDim.y) >> 3;
  int swz = (lin & 7) * cpx + (lin >> 3);
  const int m0 = (swz / gx) * 256;
  const int n0 = (swz % gx) * 256;
  const int NT = K >> 6;
  const int HMAX = NT << 2;
  const int rbB = (wn & 1) * 64;

  f32x4 acc[8][4] = {};
  bf16x8 a0[4][2], a1[4][2], bb[4][2];

#pragma unroll
  for (int j = 0; j < 5; ++j)
    stage_half(A, Bt, lds9, j, j, m0, n0, K, HMAX, tid, wid);

  int j0 = 0;  // slot of half 4t
  for (int t = 0; t < NT; ++t) {
    const int sAw = mod9(j0 + wm);
    const int sBw = mod9(j0 + 2 + (wn >> 1));
    asm volatile("s_waitcnt vmcnt(2)" ::: "memory");
    __builtin_amdgcn_sched_barrier(0);
    __builtin_amdgcn_s_barrier();
    __builtin_amdgcn_sched_barrier(0);
    // ---- phase 1: ds A mf0-3 (8) + B nf0-1 (4); stage 4t+5; MFMA 16 ----
#pragma unroll
    for (int mf = 0; mf < 4; ++mf)
#pragma unroll
      for (int kk = 0; kk < 2; ++kk) {
        int ra = mf * 16 + sl;
        a0[mf][kk] = *reinterpret_cast<const bf16x8*>(
            &lds9[sAw * 8192 + ra * 64 + (((kk * 4 + hi) ^ (ra & 7)) * 8)]);
      }
#pragma unroll
    for (int nf = 0; nf < 2; ++nf)
#pragma unroll
      for (int kk = 0; kk < 2; ++kk) {
        int rb = rbB + nf * 16 + sl;
        bb[nf][kk] = *reinterpret_cast<const bf16x8*>(
            &lds9[sBw * 8192 + rb * 64 + (((kk * 4 + hi) ^ (rb & 7)) * 8)]);
      }
    stage_half(A, Bt, lds9, 4 * t + 5, mod9(j0 + 5), m0, n0, K, HMAX, tid, wid);
    asm volatile("s_waitcnt lgkmcnt(0)" ::: "memory");
    __builtin_amdgcn_sched_barrier(0);
    __builtin_amdgcn_s_setprio(1);
#pragma unroll
    for (int mf = 0; mf < 4; ++mf)
#pragma unroll
      for (int nf = 0; nf < 2; ++nf)
#pragma unroll
        for (int kk = 0; kk < 2; ++kk)
          acc[mf][nf] = MFMA16(a0[mf][kk], bb[nf][kk], acc[mf][nf]);
    __builtin_amdgcn_s_setprio(0);
    __builtin_amdgcn_sched_barrier(0);
    // ---- phase 2: ds B nf2-3 (4); stage 4t+6; MFMA 16 ----
#pragma unroll
    for (int nf = 2; nf < 4; ++nf)
#pragma unroll
      for (int kk = 0; kk < 2; ++kk) {
        int rb = rbB + nf * 16 + sl;
        bb[nf][kk] = *reinterpret_cast<const bf16x8*>(
            &lds9[sBw * 8192 + rb * 64 + (((kk * 4 + hi) ^ (rb & 7)) * 8)]);
      }
    stage_half(A, Bt, lds9, 4 * t + 6, mod9(j0 + 6), m0, n0, K, HMAX, tid, wid);
    asm volatile("s_waitcnt lgkmcnt(0)" ::: "memory");
    __builtin_amdgcn_sched_barrier(0);
    __builtin_amdgcn_s_setprio(1);
#pragma unroll
    for (int mf = 0; mf < 4; ++mf)
#pragma unroll
      for (int nf = 2; nf < 4; ++nf)
#pragma unroll
        for (int kk = 0; kk < 2; ++kk)
          acc[mf][nf] = MFMA16(a0[mf][kk], bb[nf][kk], acc[mf][nf]);
    __builtin_amdgcn_s_setprio(0);
    __builtin_amdgcn_sched_barrier(0);
    // ---- phase 3: ds A mf4-7 (8); stage 4t+7; MFMA 16 ----
#pragma unroll
    for (int mf = 0; mf < 4; ++mf)
#pragma unroll
      for (int kk = 0; kk < 2; ++kk) {
        int ra = (mf + 4) * 16 + sl;
        a1[mf][kk] = *reinterpret_cast<const bf16x8*>(
            &lds9[sAw * 8192 + ra * 64 + (((kk * 4 + hi) ^ (ra & 7)) * 8)]);
      }
    stage_half(A, Bt, lds9, 4 * t + 7, mod9(j0 + 7), m0, n0, K, HMAX, tid, wid);
    asm volatile("s_waitcnt lgkmcnt(0)" ::: "memory");
    __builtin_amdgcn_sched_barrier(0);
    __builtin_amdgcn_s_setprio(1);
#pragma unroll
    for (int mf = 0; mf < 4; ++mf)
#pragma unroll
      for (int nf = 0; nf < 2; ++nf)
#pragma unroll
        for (int kk = 0; kk < 2; ++kk)
          acc[mf + 4][nf] = MFMA16(a1[mf][kk], bb[nf][kk], acc[mf + 4][nf]);
    __builtin_amdgcn_s_setprio(0);
    __builtin_amdgcn_sched_barrier(0);
    // ---- phase 4: stage 4t+8; MFMA 16 (all frags resident) ----
    stage_half(A, Bt, lds9, 4 * t + 8, mod9(j0 + 8), m0, n0, K, HMAX, tid, wid);
    __builtin_amdgcn_s_setprio(1);
#pragma unroll
    for (int mf = 0; mf < 4; ++mf)
#pragma unroll
      for (int nf = 2; nf < 4; ++nf)
#pragma unroll
        for (int kk = 0; kk < 2; ++kk)
          acc[mf + 4][nf] = MFMA16(a1[mf][kk], bb[nf][kk], acc[mf + 4][nf]);
    __builtin_amdgcn_s_setprio(0);
    __builtin_amdgcn_sched_barrier(0);
    j0 += 4; if (j0 >= 9) j0 -= 9;
  }
  // ---- epilogue ----
#pragma unroll
  for (int mf = 0; mf < 8; ++mf)
#pragma unroll
    for (int nf = 0; nf < 4; ++nf) {
      int col = n0 + wn * 64 + nf * 16 + sl;
      if (col < N) {
#pragma unroll
        for (int r = 0; r < 4; ++r) {
          int row = m0 + wm * 128 + mf * 16 + hi * 4 + r;
          if constexpr (sizeof(TC) == 2)
            C[(size_t)row * N + col] = __float2bfloat16(acc[mf][nf][r]);
          else
            C[(size_t)row * N + col] = acc[mf][nf][r];
        }
      }
    }
}

// ================= bf16 MFMA GEMM (proven 128xBN path, GEMM-2) ==============
template <int BN, typename TC>
__global__ __launch_bounds__(256) void gemm_bf16(const unsigned short* __restrict__ A,
                                                 const unsigned short* __restrict__ Bt,
                                                 TC* __restrict__ C,
                                                 int M, int N, int K) {
  __shared__ __align__(16) unsigned short sA[128 * 64];
  __shared__ __align__(16) unsigned short sB[BN * 64];
  const int tid = threadIdx.x;
  const int lane = tid & 63, hi = lane >> 4, sl = lane & 15;
  const int wid = tid >> 6, wm = wid >> 1, wn = wid & 1;
  const int gx = gridDim.x;
  int lin = blockIdx.y * gx + blockIdx.x;
  int cpx = (gx * gridDim.y) >> 3;
  int swz = (lin & 7) * cpx + (lin >> 3);
  const int m0 = (swz / gx) * 128;
  const int n0 = (swz % gx) * BN;
  const int lrow = lane >> 3;
  const int lslot = lane & 7;
  constexpr int NCH = 16 + BN / 8;
  constexpr int PER = NCH / 4;
  constexpr int FN = BN / 32;

  f32x4 acc[4][FN] = {};
  for (int kt = 0; kt < K; kt += 64) {
    __syncthreads();
#pragma unroll
    for (int i = 0; i < PER; ++i) {
      int ch = wid * PER + i;
      if (ch < 16) {
        int r = ch * 8 + lrow;
        int g = lslot ^ (r & 7);
        gload16(&A[(size_t)(m0 + r) * K + kt + g * 8], &sA[ch * 512]);
      } else {
        int r = (ch - 16) * 8 + lrow;
        int g = lslot ^ (r & 7);
        gload16(&Bt[(size_t)(n0 + r) * K + kt + g * 8], &sB[(ch - 16) * 512]);
      }
    }
    __syncthreads();
#pragma unroll
    for (int su = 0; su < 2; ++su) {
      bf16x8 af[4], bfr[FN];
#pragma unroll
      for (int m = 0; m < 4; ++m) {
        int r = wm * 64 + m * 16 + sl;
        af[m] = *reinterpret_cast<const bf16x8*>(
            &sA[r * 64 + (((su * 4 + hi) ^ (r & 7)) * 8)]);
      }
#pragma unroll
      for (int j = 0; j < FN; ++j) {
        int r = wn * (BN / 2) + j * 16 + sl;
        bfr[j] = *reinterpret_cast<const bf16x8*>(
            &sB[r * 64 + (((su * 4 + hi) ^ (r & 7)) * 8)]);
      }
#pragma unroll
      for (int m = 0; m < 4; ++m)
#pragma unroll
        for (int j = 0; j < FN; ++j)
          acc[m][j] = MFMA16(af[m], bfr[j], acc[m][j]);
    }
  }
#pragma unroll
  for (int m = 0; m < 4; ++m)
#pragma unroll
    for (int j = 0; j < FN; ++j) {
      int col = n0 + wn * (BN / 2) + j * 16 + sl;
      if (col < N) {
#pragma unroll
        for (int r = 0; r < 4; ++r) {
          int row = m0 + wm * 64 + m * 16 + hi * 4 + r;
          if constexpr (sizeof(TC) == 2)
            C[(size_t)row * N + col] = __float2bfloat16(acc[m][j][r]);
          else
            C[(size_t)row * N + col] = acc[m][j][r];
        }
      }
    }
}

// ------------- depthwise conv (SAME, k=4, pad_lo=1) + SiLU, bf16x8 ----------
__global__ __launch_bounds__(256) void conv_silu_k(const bf16* __restrict__ proj,
                                                   const float* __restrict__ cw,
                                                   const float* __restrict__ cb,
                                                   bf16* __restrict__ convo) {
  int idx = blockIdx.x * 256 + threadIdx.x;
  int ci = idx % (CONV_DIM / 8);
  int row = idx / (CONV_DIM / 8);
  int c8 = ci * 8;
  int t = row & (S_LEN - 1);
  int b = row >> 11;
  float acc[8];
  {
    float4 b0 = *reinterpret_cast<const float4*>(&cb[c8]);
    float4 b1 = *reinterpret_cast<const float4*>(&cb[c8 + 4]);
    acc[0] = b0.x; acc[1] = b0.y; acc[2] = b0.z; acc[3] = b0.w;
    acc[4] = b1.x; acc[5] = b1.y; acc[6] = b1.z; acc[7] = b1.w;
  }
#pragma unroll
  for (int w = 0; w < 4; w++) {
    int tt = t + w - 1;
    if (tt >= 0 && tt < S_LEN) {
      U16x8 u;
      u.u = *reinterpret_cast<const uint4*>(
          &proj[(size_t)(b * S_LEN + tt) * PROJ_DIM + INTER + c8]);
      float4 w0 = *reinterpret_cast<const float4*>(&cw[w * CONV_DIM + c8]);
      float4 w1 = *reinterpret_cast<const float4*>(&cw[w * CONV_DIM + c8 + 4]);
      acc[0] += w0.x * bu2f((unsigned short)u.v[0]);
      acc[1] += w0.y * bu2f((unsigned short)u.v[1]);
      acc[2] += w0.z * bu2f((unsigned short)u.v[2]);
      acc[3] += w0.w * bu2f((unsigned short)u.v[3]);
      acc[4] += w1.x * bu2f((unsigned short)u.v[4]);
      acc[5] += w1.y * bu2f((unsigned short)u.v[5]);
      acc[6] += w1.z * bu2f((unsigned short)u.v[6]);
      acc[7] += w1.w * bu2f((unsigned short)u.v[7]);
    }
  }
  uint4 o;
  o.x = pack2(siluf(acc[0]), siluf(acc[1]));
  o.y = pack2(siluf(acc[2]), siluf(acc[3]));
  o.z = pack2(siluf(acc[4]), siluf(acc[5]));
  o.w = pack2(siluf(acc[6]), siluf(acc[7]));
  *reinterpret_cast<uint4*>(&convo[(size_t)row * CONV_DIM + c8]) = o;
}

// ---------------- dt = softplus(dt_raw + dt_bias) ----------------
__global__ __launch_bounds__(256) void dt_k(const bf16* __restrict__ proj,
                                            const float* __restrict__ dtb,
                                            float* __restrict__ dtp) {
  int idx = blockIdx.x * 256 + threadIdx.x;
  int h = idx & 63;
  int row = idx >> 6;
  float x = ldf(&proj[(size_t)row * PROJ_DIM + DT_OFF + h]) + dtb[h];
  dtp[idx] = (x > 20.f) ? x : log1pf(__expf(x));
}

// ---------------- per-chunk cumsum of A[h]*dt ----------------
__global__ __launch_bounds__(256) void acum_k(const float* __restrict__ dtp,
                                              const float* __restrict__ alog,
                                              float* __restrict__ acum) {
  __shared__ float buf[2][CHK];
  int blk = blockIdx.x;
  int c = blk & 7;
  int h = (blk >> 3) & 63;
  int b = blk >> 9;
  int tid = threadIdx.x;
  int row0 = b * S_LEN + c * CHK;
  float a = -__expf(alog[h]);
  buf[0][tid] = a * dtp[(size_t)(row0 + tid) * NH + h];
  __syncthreads();
  int cur = 0;
#pragma unroll
  for (int off = 1; off < 256; off <<= 1) {
    float nv = buf[cur][tid];
    if (tid >= off) nv += buf[cur][tid - off];
    buf[cur ^ 1][tid] = nv;
    cur ^= 1;
    __syncthreads();
  }
  acum[(size_t)blk * CHK + tid] = buf[cur][tid];
}

// ======== per-chunk states via MFMA ====
__global__ __launch_bounds__(256) void chunk_states_mfma(const bf16* __restrict__ convo,
                                                         const float* __restrict__ dtp,
                                                         const float* __restrict__ acum,
                                                         float* __restrict__ cs) {
  __shared__ float sAc[CHK];
  __shared__ float sDtf[CHK];
  __shared__ float sEx[64];
  __shared__ __align__(16) unsigned short sHT[64 * 64];
  __shared__ __align__(16) unsigned short sBd[128 * 64];
  const int tid = threadIdx.x;
  const int lane = tid & 63, hi = lane >> 4, sl = lane & 15;
  const int wid = tid >> 6, wm = wid >> 1, wn = wid & 1;
  const int blk = blockIdx.x;
  const int h = blk & 63, bc = blk >> 6, c = bc & 7, b = bc >> 3, g = h >> 3;
  const int row0 = b * S_LEN + c * CHK;
  sAc[tid] = acum[((size_t)((b * NH + h) * NC + c)) * CHK + tid];
  sDtf[tid] = dtp[(size_t)(row0 + tid) * NH + h];
  f32x4 acc[2][4] = {};
  for (int ts = 0; ts < 4; ++ts) {
    __syncthreads();
    if (tid < 64) sEx[tid] = __expf(sAc[CHK - 1] - sAc[ts * 64 + tid]);
    __syncthreads();
#pragma unroll
    for (int it = 0; it < 2; ++it) {
      int cid = tid + it * 256;
      int t = cid >> 3, p8 = (cid & 7) * 8;
      U16x8 u;
      u.u = *reinterpret_cast<const uint4*>(
          &convo[(size_t)(row0 + ts * 64 + t) * CONV_DIM + h * HD + p8]);
      float dtv = sDtf[ts * 64 + t];
#pragma unroll
      for (int e = 0; e < 8; ++e) {
        int p = p8 + e;
        int G = (p & 7) ^ ((p >> 3) & 7);
        sHT[p * 64 + (((t >> 3) ^ G) * 8) + (t & 7)] =
            f2bu(bu2f((unsigned short)u.v[e]) * dtv);
      }
    }
#pragma unroll
    for (int it = 0; it < 4; ++it) {
      int cid = tid + it * 256;
      int t = cid >> 4, n8 = (cid & 15) * 8;
      U16x8 u;
      u.u = *reinterpret_cast<const uint4*>(
          &convo[(size_t)(row0 + ts * 64 + t) * CONV_DIM + B_OFF + g * SSZ + n8]);
      float ex = sEx[t];
#pragma unroll
      for (int e = 0; e < 8; ++e) {
        int n = n8 + e;
        int G = (n & 7) ^ ((n >> 3) & 7);
        sBd[n * 64 + (((t >> 3) ^ G) * 8) + (t & 7)] =
            f2bu(bu2f((unsigned short)u.v[e]) * ex);
      }
    }
    __syncthreads();
#pragma unroll
    for (int kc = 0; kc < 2; ++kc) {
      bf16x8 a[2], bb[4];
#pragma unroll
      for (int m = 0; m < 2; ++m) {
        int p = wm * 32 + m * 16 + sl;
        int G = (p & 7) ^ ((p >> 3) & 7);
        a[m] = *reinterpret_cast<const bf16x8*>(
            &sHT[p * 64 + (((kc * 4 + hi) ^ G) * 8)]);
      }
#pragma unroll
      for (int j = 0; j < 4; ++j) {
        int n = wn * 64 + j * 16 + sl;
        int G = (n & 7) ^ ((n >> 3) & 7);
        bb[j] = *reinterpret_cast<const bf16x8*>(
            &sBd[n * 64 + (((kc * 4 + hi) ^ G) * 8)]);
      }
#pragma unroll
      for (int m = 0; m < 2; ++m)
#pragma unroll
        for (int j = 0; j < 4; ++j) acc[m][j] = MFMA16(a[m], bb[j], acc[m][j]);
    }
  }
  size_t base = (size_t)blk * HD * SSZ;
#pragma unroll
  for (int m = 0; m < 2; ++m)
#pragma unroll
    for (int j = 0; j < 4; ++j)
#pragma unroll
      for (int r = 0; r < 4; ++r) {
        int p = wm * 32 + m * 16 + hi * 4 + r;
        int n = wn * 64 + j * 16 + sl;
        cs[base + (size_t)p * SSZ + n] = acc[m][j][r];
      }
}

// ---------------- inter-chunk recurrence (in-place) ----------------
__global__ __launch_bounds__(256) void chunk_rec_k(const float* __restrict__ acum,
                                                   float* __restrict__ cs) {
  int idx = blockIdx.x * 256 + threadIdx.x;
  int n = idx & 127;
  int p = (idx >> 7) & 63;
  int h = (idx >> 13) & 63;
  int b = idx >> 19;
  float run = 0.f;
#pragma unroll
  for (int c = 0; c < NC; c++) {
    size_t off = ((size_t)(((b * NC + c) * NH + h) * HD + p)) * SSZ + n;
    float csv = cs[off];
    float al = acum[((size_t)((b * NH + h) * NC + c)) * CHK + (CHK - 1)];
    cs[off] = run;
    run = run * __expf(al) + csv;
  }
}

// ================= chunk output via MFMA (flash-style) =======================
__global__ __launch_bounds__(256) void chunk_out_mfma(const bf16* __restrict__ convo,
                                                      const float* __restrict__ dtp,
                                                      const float* __restrict__ acum,
                                                      const float* __restrict__ cs,
                                                      const float* __restrict__ Dp,
                                                      bf16* __restrict__ yb) {
  __shared__ float sAc[CHK];
  __shared__ float sDt[CHK];
  __shared__ __align__(16) unsigned short sB[64 * 128];
  __shared__ __align__(16) unsigned short sH[64 * 64];
  __shared__ __align__(16) unsigned short sW[4 * 64 * 64];
  const int tid = threadIdx.x;
  const int lane = tid & 63, hi = lane >> 4, sl = lane & 15;
  const int wid = tid >> 6;
  const int blk = blockIdx.x;
  const int h = blk & 63;
  const int bc = blk >> 6;
  const int c = bc & 7;
  const int b = bc >> 3;
  const int g = h >> 3;
  const int row0 = b * S_LEN + c * CHK;
  unsigned short* sWp = &sW[wid * 4096];

  sAc[tid] = acum[((size_t)((b * NH + h) * NC + c)) * CHK + tid];
  sDt[tid] = dtp[(size_t)(row0 + tid) * NH + h];

  bf16x8 cf[4][4];
#pragma unroll
  for (int m = 0; m < 4; ++m)
#pragma unroll
    for (int kc = 0; kc < 4; ++kc) {
      int l = wid * 64 + m * 16 + sl;
      U16x8 u;
      u.u = *reinterpret_cast<const uint4*>(
          &convo[(size_t)(row0 + l) * CONV_DIM + C_OFF + g * SSZ + kc * 32 + hi * 8]);
      cf[m][kc] = u.v;
    }

  f32x4 acc[4][4] = {};

  for (int st = 0; st < 4; ++st) {
    __syncthreads();
#pragma unroll
    for (int it = 0; it < 4; ++it) {
      int cid = tid + it * 256;
      int s = cid >> 4, gr = cid & 15;
      const uint4* p = reinterpret_cast<const uint4*>(
          &convo[(size_t)(row0 + st * 64 + s) * CONV_DIM + B_OFF + g * SSZ + gr * 8]);
      *reinterpret_cast<uint4*>(&sB[s * 128 + (gr ^ (s & 7)) * 8]) = *p;
    }
#pragma unroll
    for (int it = 0; it < 16; ++it) {
      int cid = tid + it * 256;
      int s = cid >> 6, pp = cid & 63;
      float v = ldf(&convo[(size_t)(row0 + st * 64 + s) * CONV_DIM + h * HD + pp]) *
                sDt[st * 64 + s];
      sH[pp * 64 + (((s >> 3) ^ (pp & 7)) * 8) + (s & 7)] = f2bu(v);
    }
    __syncthreads();
    if (wid >= st) {
#pragma unroll
      for (int sf = 0; sf < 4; ++sf) {
        f32x4 d[4] = {};
#pragma unroll
        for (int kc = 0; kc < 4; ++kc) {
          int srow = sf * 16 + sl;
          bf16x8 bfv = *reinterpret_cast<const bf16x8*>(
              &sB[srow * 128 + (((kc * 4 + hi) ^ (srow & 7)) * 8)]);
#pragma unroll
          for (int m = 0; m < 4; ++m) d[m] = MFMA16(cf[m][kc], bfv, d[m]);
        }
        int s_loc = sf * 16 + sl;
        int s_glob = st * 64 + s_loc;
        float acS = sAc[s_glob];
        bool diag = (st == wid);
#pragma unroll
        for (int m = 0; m < 4; ++m)
#pragma unroll
          for (int r = 0; r < 4; ++r) {
            int l_loc = m * 16 + hi * 4 + r;
            int l_glob = wid * 64 + l_loc;
            float e = __expf(sAc[l_glob] - acS);
            float v = d[m][r] * e;
            if (diag && s_glob > l_glob) v = 0.f;
            sWp[l_loc * 64 + (((s_loc >> 3) ^ (l_loc & 7)) * 8) + (s_loc & 7)] = f2bu(v);
          }
      }
    }
    __syncthreads();
    if (wid >= st) {
#pragma unroll
      for (int kc = 0; kc < 2; ++kc) {
        bf16x8 a[4], bb[4];
#pragma unroll
        for (int m = 0; m < 4; ++m) {
          int l = m * 16 + sl;
          a[m] = *reinterpret_cast<const bf16x8*>(
              &sWp[l * 64 + (((kc * 4 + hi) ^ (l & 7)) * 8)]);
        }
#pragma unroll
        for (int j = 0; j < 4; ++j) {
          int p = j * 16 + sl;
          bb[j] = *reinterpret_cast<const bf16x8*>(
              &sH[p * 64 + (((kc * 4 + hi) ^ (p & 7)) * 8)]);
        }
#pragma unroll
        for (int m = 0; m < 4; ++m)
#pragma unroll
          for (int j = 0; j < 4; ++j) acc[m][j] = MFMA16(a[m], bb[j], acc[m][j]);
      }
    }
  }

  __syncthreads();
  {
    size_t sinbase = ((size_t)(((b * NC + c) * NH + h) * HD)) * SSZ;
#pragma unroll
    for (int it = 0; it < 8; ++it) {
      int cid = tid + it * 256;
      int p = cid >> 5, q = cid & 31;
      float4 v = *reinterpret_cast<const float4*>(&cs[sinbase + (size_t)p * SSZ + q * 4]);
      uint2 val = make_uint2(pack2(v.x, v.y), pack2(v.z, v.w));
      *reinterpret_cast<uint2*>(&sB[p * 128 + ((q >> 1) ^ (p & 7)) * 8 + (q & 1) * 4]) = val;
    }
  }
  __syncthreads();
#pragma unroll
  for (int m = 0; m < 4; ++m) {
    float e = __expf(sAc[wid * 64 + m * 16 + sl]);
#pragma unroll
    for (int kc = 0; kc < 4; ++kc) {
      bf16x8 fv = cf[m][kc];
#pragma unroll
      for (int ei = 0; ei < 8; ++ei) {
        unsigned short us = (unsigned short)fv[ei];
        fv[ei] = (short)f2bu(bu2f(us) * e);
      }
      cf[m][kc] = fv;
    }
  }
#pragma unroll
  for (int kc = 0; kc < 4; ++kc) {
    bf16x8 bb[4];
#pragma unroll
    for (int j = 0; j < 4; ++j) {
      int p = j * 16 + sl;
      bb[j] = *reinterpret_cast<const bf16x8*>(
          &sB[p * 128 + (((kc * 4 + hi) ^ (p & 7)) * 8)]);
    }
#pragma unroll
    for (int m = 0; m < 4; ++m)
#pragma unroll
      for (int j = 0; j < 4; ++j) acc[m][j] = MFMA16(cf[m][kc], bb[j], acc[m][j]);
  }

  float Dh = Dp[h];
#pragma unroll
  for (int m = 0; m < 4; ++m)
#pragma unroll
    for (int j = 0; j < 4; ++j)
#pragma unroll
      for (int r = 0; r < 4; ++r) {
        int l_glob = wid * 64 + m * 16 + hi * 4 + r;
        size_t row = (size_t)(row0 + l_glob);
        int pg = j * 16 + sl;
        float hraw = ldf(&convo[row * CONV_DIM + h * HD + pg]);
        yb[row * INTER + h * HD + pg] = __float2bfloat16(acc[m][j][r] + Dh * hraw);
      }
}

// ------------- gate SiLU + RMSNorm (in-place on yb), bf16x8 -------------
__global__ __launch_bounds__(256) void norm_k(const bf16* __restrict__ proj,
                                              const float* __restrict__ nw,
                                              bf16* __restrict__ yb) {
  int row = blockIdx.x;
  int tid = threadIdx.x;
  float vals[16];
  float ss = 0.f;
#pragma unroll
  for (int half = 0; half < 2; half++) {
    int colb = tid * 8 + half * 2048;
    U16x8 gy, gg;
    gy.u = *reinterpret_cast<const uint4*>(&yb[(size_t)row * INTER + colb]);
    gg.u = *reinterpret_cast<const uint4*>(&proj[(size_t)row * PROJ_DIM + colb]);
#pragma unroll
    for (int e = 0; e < 8; e++) {
      float yf = bu2f((unsigned short)gy.v[e]) * siluf(bu2f((unsigned short)gg.v[e]));
      vals[half * 8 + e] = yf;
      ss += yf * yf;
    }
  }
#pragma unroll
  for (int off = 32; off > 0; off >>= 1) ss += __shfl_down(ss, off);
  __shared__ float red[4];
  if ((tid & 63) == 0) red[tid >> 6] = ss;
  __syncthreads();
  float tot = red[0] + red[1] + red[2] + red[3];
  float scale = rsqrtf(tot * (1.f / INTER) + 1e-6f);
#pragma unroll
  for (int half = 0; half < 2; half++) {
    int colb = tid * 8 + half * 2048;
    float4 w0 = *reinterpret_cast<const float4*>(&nw[colb]);
    float4 w1 = *reinterpret_cast<const float4*>(&nw[colb + 4]);
    float s0 = vals[half * 8 + 0] * scale * w0.x, s1 = vals[half * 8 + 1] * scale * w0.y;
    float s2 = vals[half * 8 + 2] * scale * w0.z, s3 = vals[half * 8 + 3] * scale * w0.w;
    float s4 = vals[half * 8 + 4] * scale * w1.x, s5 = vals[half * 8 + 5] * scale * w1.y;
    float s6 = vals[half * 8 + 6] * scale * w1.z, s7 = vals[half * 8 + 7] * scale * w1.w;
    uint4 o = make_uint4(pack2(s0, s1), pack2(s2, s3), pack2(s4, s5), pack2(s6, s7));
    *reinterpret_cast<uint4*>(&yb[(size_t)row * INTER + colb]) = o;
  }
}

extern "C" void kernel_launch(void* const* d_in, const int* in_sizes, int n_in,
                              void* d_out, int out_size, void* d_ws, size_t ws_size,
                              hipStream_t stream) {
  const float* x     = (const float*)d_in[0];
  const float* wproj = (const float*)d_in[1];
  const float* cw    = (const float*)d_in[2];
  const float* cb    = (const float*)d_in[3];
  const float* dtb   = (const float*)d_in[4];
  const float* alog  = (const float*)d_in[5];
  const float* Dp    = (const float*)d_in[6];
  const float* nw    = (const float*)d_in[7];
  const float* wout  = (const float*)d_in[8];
  float* out = (float*)d_out;
  char* ws = (char*)d_ws;

  // persistent layout (~195 MiB, proven safe)
  bf16*  proj  = (bf16*)(ws);                    // 84,410,368 B
  bf16*  convo = (bf16*)(ws + 84410368);         // 50,331,648 B
  bf16*  yb    = (bf16*)(ws + 134742016);        // 33,554,432 B
  float* dtp   = (float*)(ws + 168296448);       //  1,048,576 B
  float* acum  = (float*)(ws + 169345024);       //  1,048,576 B
  float* cs    = (float*)(ws + 170393600);       // 33,554,432 B
  // liveness-overlapped temporaries:
  unsigned short* Wt1 = (unsigned short*)(ws + 84410368);   // in convo (10496x2048 = 43.0MB < 50.3MB)
  unsigned short* xb  = (unsigned short*)(ws + 134742016);  // in yb
  unsigned short* Wt2 = (unsigned short*)(ws + 170393600);  // in cs

  hipFuncSetAttribute(reinterpret_cast<const void*>(&gemm_8ph<bf16>),
                      hipFuncAttributeMaxDynamicSharedMemorySize, 147456);

  cvt_bf16_k<<<dim3(2048), 256, 0, stream>>>(x, xb, ROWS * HIDDEN / 4);
  wT_k<<<dim3(PROJ_PAD / 64, HIDDEN / 64), 256, 0, stream>>>(wproj, Wt1, HIDDEN, PROJ_DIM);
  gemm_8ph<bf16><<<dim3(PROJ_PAD / 256, ROWS / 256), 512, 147456, stream>>>(
      xb, Wt1, proj, ROWS, PROJ_DIM, HIDDEN);
  conv_silu_k<<<dim3(ROWS * CONV_DIM / 8 / 256), 256, 0, stream>>>(proj, cw, cb, convo);
  dt_k<<<dim3(ROWS * NH / 256), 256, 0, stream>>>(proj, dtb, dtp);
  acum_k<<<dim3(2 * NH * NC), 256, 0, stream>>>(dtp, alog, acum);
  chunk_states_mfma<<<dim3(2 * NC * NH), 256, 0, stream>>>(convo, dtp, acum, cs);
  chunk_rec_k<<<dim3(2 * NH * HD * SSZ / 256), 256, 0, stream>>>(acum, cs);
  chunk_out_mfma<<<dim3(2 * NC * NH), 256, 0, stream>>>(convo, dtp, acum, cs, Dp, yb);
  norm_k<<<dim3(ROWS), 256, 0, stream>>>(proj, nw, yb);
  wT_k<<<dim3(HIDDEN / 64, INTER / 64), 256, 0, stream>>>(wout, Wt2, INTER, HIDDEN);
  gemm_bf16<64, float><<<dim3(HIDDEN / 64, ROWS / 128), 256, 0, stream>>>(
      (const unsigned short*)yb, Wt2, out, ROWS, HIDDEN, INTER);
}

// Round 8
// 503.718 us; speedup vs baseline: 16.5520x; 1.0224x over previous
//
#include <hip/hip_runtime.h>
#include <hip/hip_bf16.h>

// Mamba2 mixer — 256²/8-phase MFMA GEMMs (ring-9 LDS, counted vmcnt, split-K
// for out-proj), MFMA chunk_out/chunk_states.
// B=2 S=2048 HID=2048 INTER=4096 NH=64 HD=64 NG=8 SS=128 CK=4 CH=256 NC=8

#define S_LEN 2048
#define HIDDEN 2048
#define INTER 4096
#define NH 64
#define HD 64
#define NG 8
#define SSZ 128
#define CONV_DIM 6144
#define PROJ_DIM 10304
#define PROJ_PAD 10496     // 41*256
#define NC 8
#define CHK 256
#define ROWS 4096          // B*S
#define DT_OFF 10240       // INTER + CONV_DIM
#define B_OFF 4096         // B section inside conv block
#define C_OFF 5120         // C section inside conv block

typedef __hip_bfloat16 bf16;
typedef __attribute__((ext_vector_type(8))) short bf16x8;
typedef __attribute__((ext_vector_type(4))) float f32x4;
#define MFMA16(a, b, c) __builtin_amdgcn_mfma_f32_16x16x32_bf16(a, b, c, 0, 0, 0)

union U16x8 { uint4 u; bf16x8 v; };

__device__ __forceinline__ float siluf(float x) { return x / (1.f + __expf(-x)); }
__device__ __forceinline__ float ldf(const float* p) { return *p; }
__device__ __forceinline__ float ldf(const bf16* p) { return __bfloat162float(*p); }
__device__ __forceinline__ unsigned short f2bu(float x) {
  bf16 h = __float2bfloat16(x);
  return __builtin_bit_cast(unsigned short, h);
}
__device__ __forceinline__ float bu2f(unsigned short u) {
  return __uint_as_float(((unsigned)u) << 16);
}
__device__ __forceinline__ unsigned pack2(float lo, float hi) {
  return ((unsigned)f2bu(hi) << 16) | f2bu(lo);
}
// async global->LDS, 16B per lane; LDS dst wave-uniform (HW adds lane*16)
__device__ __forceinline__ void gload16(const void* g, void* l) {
  __builtin_amdgcn_global_load_lds((const __attribute__((address_space(1))) unsigned*)g,
                                   (__attribute__((address_space(3))) unsigned*)l, 16, 0, 0);
}

// ---------------- fp32 -> bf16 bulk convert ----------------
__global__ __launch_bounds__(256) void cvt_bf16_k(const float* __restrict__ x,
                                                  unsigned short* __restrict__ o, int n4) {
  int idx = blockIdx.x * 256 + threadIdx.x;
  int stride = gridDim.x * 256;
  for (int i = idx; i < n4; i += stride) {
    float4 v = reinterpret_cast<const float4*>(x)[i];
    uint2 u = make_uint2(pack2(v.x, v.y), pack2(v.z, v.w));
    reinterpret_cast<uint2*>(o)[i] = u;
  }
}

// ---------------- split-K reduce: out = p0 + p1 ----------------
__global__ __launch_bounds__(256) void add_k(const float* __restrict__ p0,
                                             const float* __restrict__ p1,
                                             float* __restrict__ o, int n4) {
  int idx = blockIdx.x * 256 + threadIdx.x;
  int stride = gridDim.x * 256;
  for (int i = idx; i < n4; i += stride) {
    float4 a = reinterpret_cast<const float4*>(p0)[i];
    float4 b = reinterpret_cast<const float4*>(p1)[i];
    reinterpret_cast<float4*>(o)[i] =
        make_float4(a.x + b.x, a.y + b.y, a.z + b.z, a.w + b.w);
  }
}

// ------------- weight transpose+convert: W[K][N] f32 -> Wt[NP][K] bf16 ----------
__global__ __launch_bounds__(256) void wT_k(const float* __restrict__ W,
                                            unsigned short* __restrict__ Wt,
                                            int K, int N) {
  __shared__ unsigned short t[64][72];
  int n0 = blockIdx.x * 64, k0 = blockIdx.y * 64;
  int tid = threadIdx.x;
#pragma unroll
  for (int i = 0; i < 16; ++i) {
    int idx = tid + i * 256;
    int kr = idx >> 6, nc = idx & 63;
    float v = (n0 + nc < N) ? W[(size_t)(k0 + kr) * N + n0 + nc] : 0.f;
    t[kr][nc] = f2bu(v);
  }
  __syncthreads();
#pragma unroll
  for (int i = 0; i < 16; ++i) {
    int idx = tid + i * 256;
    int nr = idx >> 6, kc = idx & 63;
    Wt[(size_t)(n0 + nr) * K + k0 + kc] = t[kc][nr];
  }
}

// =========================== 256² / 8-phase GEMM ============================
// C[M,N] = A[M,K] @ Wt[N,K]^T over K-range [z*ksplit, (z+1)*ksplit);
// z = blockIdx.z writes to C + z*M*N (split-K partials; z-dim 1 => plain GEMM).
// 512 thr (8 waves 2x4), BK=64. LDS ring of 9 half-tiles (16KB = 128rows x 64k),
// slot = half % 9. Tile t halves: 4t+{0,1}=A[0:128),[128:256); 4t+{2,3}=B.
// While computing tile t, stage halves 4t+5..4t+8. Entry: vmcnt(2)+barrier.
__device__ __forceinline__ int mod9(int x) { return x >= 9 ? x - 9 : x; }

__device__ __forceinline__ void stage_half(const unsigned short* __restrict__ A,
                                           const unsigned short* __restrict__ Bt,
                                           unsigned short* lds9, int hj, int slot,
                                           int m0, int n0, int K, int kbase, int hmax,
                                           int tid, int wid) {
  if (hj >= hmax) return;
  const int t = hj >> 2, i = hj & 3;
  const unsigned short* src = (i < 2) ? A : Bt;
  const int br = ((i < 2) ? m0 : n0) + (i & 1) * 128;
  const int g = (tid & 7) ^ ((tid >> 3) & 7);   // inverse-swizzled source granule
#pragma unroll
  for (int r = 0; r < 2; ++r) {
    int row = r * 64 + (tid >> 3);
    gload16(&src[(size_t)(br + row) * K + kbase + t * 64 + g * 8],
            &lds9[slot * 8192 + r * 4096 + wid * 512]);
  }
}

template <typename TC>
__global__ __launch_bounds__(512, 2) void gemm_8ph(const unsigned short* __restrict__ A,
                                                   const unsigned short* __restrict__ Bt,
                                                   TC* __restrict__ C,
                                                   int M, int N, int K, int ksplit) {
  extern __shared__ unsigned short lds9[];
  const int tid = threadIdx.x;
  const int lane = tid & 63, hi = lane >> 4, sl = lane & 15;
  const int wid = tid >> 6;
  const int wm = wid >> 2, wn = wid & 3;
  const int gx = gridDim.x;
  int lin = blockIdx.y * gx + blockIdx.x;
  int cpx = (gx * gridDim.y) >> 3;
  int swz = (lin & 7) * cpx + (lin >> 3);
  const int m0 = (swz / gx) * 256;
  const int n0 = (swz % gx) * 256;
  const int kbase = blockIdx.z * ksplit;
  TC* Cz = C + (size_t)blockIdx.z * M * N;
  const int NT = ksplit >> 6;
  const int HMAX = NT << 2;
  const int rbB = (wn & 1) * 64;

  f32x4 acc[8][4] = {};
  bf16x8 a0[4][2], a1[4][2], bb[4][2];

#pragma unroll
  for (int j = 0; j < 5; ++j)
    stage_half(A, Bt, lds9, j, j, m0, n0, K, kbase, HMAX, tid, wid);

  int j0 = 0;  // slot of half 4t
  for (int t = 0; t < NT; ++t) {
    const int sAw = mod9(j0 + wm);
    const int sBw = mod9(j0 + 2 + (wn >> 1));
    asm volatile("s_waitcnt vmcnt(2)" ::: "memory");
    __builtin_amdgcn_sched_barrier(0);
    __builtin_amdgcn_s_barrier();
    __builtin_amdgcn_sched_barrier(0);
    // ---- phase 1: ds A mf0-3 (8) + B nf0-1 (4); stage 4t+5; MFMA 16 ----
#pragma unroll
    for (int mf = 0; mf < 4; ++mf)
#pragma unroll
      for (int kk = 0; kk < 2; ++kk) {
        int ra = mf * 16 + sl;
        a0[mf][kk] = *reinterpret_cast<const bf16x8*>(
            &lds9[sAw * 8192 + ra * 64 + (((kk * 4 + hi) ^ (ra & 7)) * 8)]);
      }
#pragma unroll
    for (int nf = 0; nf < 2; ++nf)
#pragma unroll
      for (int kk = 0; kk < 2; ++kk) {
        int rb = rbB + nf * 16 + sl;
        bb[nf][kk] = *reinterpret_cast<const bf16x8*>(
            &lds9[sBw * 8192 + rb * 64 + (((kk * 4 + hi) ^ (rb & 7)) * 8)]);
      }
    stage_half(A, Bt, lds9, 4 * t + 5, mod9(j0 + 5), m0, n0, K, kbase, HMAX, tid, wid);
    asm volatile("s_waitcnt lgkmcnt(0)" ::: "memory");
    __builtin_amdgcn_sched_barrier(0);
    __builtin_amdgcn_s_setprio(1);
#pragma unroll
    for (int mf = 0; mf < 4; ++mf)
#pragma unroll
      for (int nf = 0; nf < 2; ++nf)
#pragma unroll
        for (int kk = 0; kk < 2; ++kk)
          acc[mf][nf] = MFMA16(a0[mf][kk], bb[nf][kk], acc[mf][nf]);
    __builtin_amdgcn_s_setprio(0);
    __builtin_amdgcn_sched_barrier(0);
    // ---- phase 2: ds B nf2-3 (4); stage 4t+6; MFMA 16 ----
#pragma unroll
    for (int nf = 2; nf < 4; ++nf)
#pragma unroll
      for (int kk = 0; kk < 2; ++kk) {
        int rb = rbB + nf * 16 + sl;
        bb[nf][kk] = *reinterpret_cast<const bf16x8*>(
            &lds9[sBw * 8192 + rb * 64 + (((kk * 4 + hi) ^ (rb & 7)) * 8)]);
      }
    stage_half(A, Bt, lds9, 4 * t + 6, mod9(j0 + 6), m0, n0, K, kbase, HMAX, tid, wid);
    asm volatile("s_waitcnt lgkmcnt(0)" ::: "memory");
    __builtin_amdgcn_sched_barrier(0);
    __builtin_amdgcn_s_setprio(1);
#pragma unroll
    for (int mf = 0; mf < 4; ++mf)
#pragma unroll
      for (int nf = 2; nf < 4; ++nf)
#pragma unroll
        for (int kk = 0; kk < 2; ++kk)
          acc[mf][nf] = MFMA16(a0[mf][kk], bb[nf][kk], acc[mf][nf]);
    __builtin_amdgcn_s_setprio(0);
    __builtin_amdgcn_sched_barrier(0);
    // ---- phase 3: ds A mf4-7 (8); stage 4t+7; MFMA 16 ----
#pragma unroll
    for (int mf = 0; mf < 4; ++mf)
#pragma unroll
      for (int kk = 0; kk < 2; ++kk) {
        int ra = (mf + 4) * 16 + sl;
        a1[mf][kk] = *reinterpret_cast<const bf16x8*>(
            &lds9[sAw * 8192 + ra * 64 + (((kk * 4 + hi) ^ (ra & 7)) * 8)]);
      }
    stage_half(A, Bt, lds9, 4 * t + 7, mod9(j0 + 7), m0, n0, K, kbase, HMAX, tid, wid);
    asm volatile("s_waitcnt lgkmcnt(0)" ::: "memory");
    __builtin_amdgcn_sched_barrier(0);
    __builtin_amdgcn_s_setprio(1);
#pragma unroll
    for (int mf = 0; mf < 4; ++mf)
#pragma unroll
      for (int nf = 0; nf < 2; ++nf)
#pragma unroll
        for (int kk = 0; kk < 2; ++kk)
          acc[mf + 4][nf] = MFMA16(a1[mf][kk], bb[nf][kk], acc[mf + 4][nf]);
    __builtin_amdgcn_s_setprio(0);
    __builtin_amdgcn_sched_barrier(0);
    // ---- phase 4: stage 4t+8; MFMA 16 (all frags resident) ----
    stage_half(A, Bt, lds9, 4 * t + 8, mod9(j0 + 8), m0, n0, K, kbase, HMAX, tid, wid);
    __builtin_amdgcn_s_setprio(1);
#pragma unroll
    for (int mf = 0; mf < 4; ++mf)
#pragma unroll
      for (int nf = 2; nf < 4; ++nf)
#pragma unroll
        for (int kk = 0; kk < 2; ++kk)
          acc[mf + 4][nf] = MFMA16(a1[mf][kk], bb[nf][kk], acc[mf + 4][nf]);
    __builtin_amdgcn_s_setprio(0);
    __builtin_amdgcn_sched_barrier(0);
    j0 += 4; if (j0 >= 9) j0 -= 9;
  }
  // ---- epilogue ----
#pragma unroll
  for (int mf = 0; mf < 8; ++mf)
#pragma unroll
    for (int nf = 0; nf < 4; ++nf) {
      int col = n0 + wn * 64 + nf * 16 + sl;
      if (col < N) {
#pragma unroll
        for (int r = 0; r < 4; ++r) {
          int row = m0 + wm * 128 + mf * 16 + hi * 4 + r;
          if constexpr (sizeof(TC) == 2)
            Cz[(size_t)row * N + col] = __float2bfloat16(acc[mf][nf][r]);
          else
            Cz[(size_t)row * N + col] = acc[mf][nf][r];
        }
      }
    }
}

// ------------- depthwise conv (SAME, k=4, pad_lo=1) + SiLU, bf16x8 ----------
__global__ __launch_bounds__(256) void conv_silu_k(const bf16* __restrict__ proj,
                                                   const float* __restrict__ cw,
                                                   const float* __restrict__ cb,
                                                   bf16* __restrict__ convo) {
  int idx = blockIdx.x * 256 + threadIdx.x;
  int ci = idx % (CONV_DIM / 8);
  int row = idx / (CONV_DIM / 8);
  int c8 = ci * 8;
  int t = row & (S_LEN - 1);
  int b = row >> 11;
  float acc[8];
  {
    float4 b0 = *reinterpret_cast<const float4*>(&cb[c8]);
    float4 b1 = *reinterpret_cast<const float4*>(&cb[c8 + 4]);
    acc[0] = b0.x; acc[1] = b0.y; acc[2] = b0.z; acc[3] = b0.w;
    acc[4] = b1.x; acc[5] = b1.y; acc[6] = b1.z; acc[7] = b1.w;
  }
#pragma unroll
  for (int w = 0; w < 4; w++) {
    int tt = t + w - 1;
    if (tt >= 0 && tt < S_LEN) {
      U16x8 u;
      u.u = *reinterpret_cast<const uint4*>(
          &proj[(size_t)(b * S_LEN + tt) * PROJ_DIM + INTER + c8]);
      float4 w0 = *reinterpret_cast<const float4*>(&cw[w * CONV_DIM + c8]);
      float4 w1 = *reinterpret_cast<const float4*>(&cw[w * CONV_DIM + c8 + 4]);
      acc[0] += w0.x * bu2f((unsigned short)u.v[0]);
      acc[1] += w0.y * bu2f((unsigned short)u.v[1]);
      acc[2] += w0.z * bu2f((unsigned short)u.v[2]);
      acc[3] += w0.w * bu2f((unsigned short)u.v[3]);
      acc[4] += w1.x * bu2f((unsigned short)u.v[4]);
      acc[5] += w1.y * bu2f((unsigned short)u.v[5]);
      acc[6] += w1.z * bu2f((unsigned short)u.v[6]);
      acc[7] += w1.w * bu2f((unsigned short)u.v[7]);
    }
  }
  uint4 o;
  o.x = pack2(siluf(acc[0]), siluf(acc[1]));
  o.y = pack2(siluf(acc[2]), siluf(acc[3]));
  o.z = pack2(siluf(acc[4]), siluf(acc[5]));
  o.w = pack2(siluf(acc[6]), siluf(acc[7]));
  *reinterpret_cast<uint4*>(&convo[(size_t)row * CONV_DIM + c8]) = o;
}

// ---------------- dt = softplus(dt_raw + dt_bias) ----------------
__global__ __launch_bounds__(256) void dt_k(const bf16* __restrict__ proj,
                                            const float* __restrict__ dtb,
                                            float* __restrict__ dtp) {
  int idx = blockIdx.x * 256 + threadIdx.x;
  int h = idx & 63;
  int row = idx >> 6;
  float x = ldf(&proj[(size_t)row * PROJ_DIM + DT_OFF + h]) + dtb[h];
  dtp[idx] = (x > 20.f) ? x : log1pf(__expf(x));
}

// ---------------- per-chunk cumsum of A[h]*dt ----------------
__global__ __launch_bounds__(256) void acum_k(const float* __restrict__ dtp,
                                              const float* __restrict__ alog,
                                              float* __restrict__ acum) {
  __shared__ float buf[2][CHK];
  int blk = blockIdx.x;
  int c = blk & 7;
  int h = (blk >> 3) & 63;
  int b = blk >> 9;
  int tid = threadIdx.x;
  int row0 = b * S_LEN + c * CHK;
  float a = -__expf(alog[h]);
  buf[0][tid] = a * dtp[(size_t)(row0 + tid) * NH + h];
  __syncthreads();
  int cur = 0;
#pragma unroll
  for (int off = 1; off < 256; off <<= 1) {
    float nv = buf[cur][tid];
    if (tid >= off) nv += buf[cur][tid - off];
    buf[cur ^ 1][tid] = nv;
    cur ^= 1;
    __syncthreads();
  }
  acum[(size_t)blk * CHK + tid] = buf[cur][tid];
}

// ======== per-chunk states via MFMA ====
__global__ __launch_bounds__(256) void chunk_states_mfma(const bf16* __restrict__ convo,
                                                         const float* __restrict__ dtp,
                                                         const float* __restrict__ acum,
                                                         float* __restrict__ cs) {
  __shared__ float sAc[CHK];
  __shared__ float sDtf[CHK];
  __shared__ float sEx[64];
  __shared__ __align__(16) unsigned short sHT[64 * 64];
  __shared__ __align__(16) unsigned short sBd[128 * 64];
  const int tid = threadIdx.x;
  const int lane = tid & 63, hi = lane >> 4, sl = lane & 15;
  const int wid = tid >> 6, wm = wid >> 1, wn = wid & 1;
  const int blk = blockIdx.x;
  const int h = blk & 63, bc = blk >> 6, c = bc & 7, b = bc >> 3, g = h >> 3;
  const int row0 = b * S_LEN + c * CHK;
  sAc[tid] = acum[((size_t)((b * NH + h) * NC + c)) * CHK + tid];
  sDtf[tid] = dtp[(size_t)(row0 + tid) * NH + h];
  f32x4 acc[2][4] = {};
  for (int ts = 0; ts < 4; ++ts) {
    __syncthreads();
    if (tid < 64) sEx[tid] = __expf(sAc[CHK - 1] - sAc[ts * 64 + tid]);
    __syncthreads();
#pragma unroll
    for (int it = 0; it < 2; ++it) {
      int cid = tid + it * 256;
      int t = cid >> 3, p8 = (cid & 7) * 8;
      U16x8 u;
      u.u = *reinterpret_cast<const uint4*>(
          &convo[(size_t)(row0 + ts * 64 + t) * CONV_DIM + h * HD + p8]);
      float dtv = sDtf[ts * 64 + t];
#pragma unroll
      for (int e = 0; e < 8; ++e) {
        int p = p8 + e;
        int G = (p & 7) ^ ((p >> 3) & 7);
        sHT[p * 64 + (((t >> 3) ^ G) * 8) + (t & 7)] =
            f2bu(bu2f((unsigned short)u.v[e]) * dtv);
      }
    }
#pragma unroll
    for (int it = 0; it < 4; ++it) {
      int cid = tid + it * 256;
      int t = cid >> 4, n8 = (cid & 15) * 8;
      U16x8 u;
      u.u = *reinterpret_cast<const uint4*>(
          &convo[(size_t)(row0 + ts * 64 + t) * CONV_DIM + B_OFF + g * SSZ + n8]);
      float ex = sEx[t];
#pragma unroll
      for (int e = 0; e < 8; ++e) {
        int n = n8 + e;
        int G = (n & 7) ^ ((n >> 3) & 7);
        sBd[n * 64 + (((t >> 3) ^ G) * 8) + (t & 7)] =
            f2bu(bu2f((unsigned short)u.v[e]) * ex);
      }
    }
    __syncthreads();
#pragma unroll
    for (int kc = 0; kc < 2; ++kc) {
      bf16x8 a[2], bb[4];
#pragma unroll
      for (int m = 0; m < 2; ++m) {
        int p = wm * 32 + m * 16 + sl;
        int G = (p & 7) ^ ((p >> 3) & 7);
        a[m] = *reinterpret_cast<const bf16x8*>(
            &sHT[p * 64 + (((kc * 4 + hi) ^ G) * 8)]);
      }
#pragma unroll
      for (int j = 0; j < 4; ++j) {
        int n = wn * 64 + j * 16 + sl;
        int G = (n & 7) ^ ((n >> 3) & 7);
        bb[j] = *reinterpret_cast<const bf16x8*>(
            &sBd[n * 64 + (((kc * 4 + hi) ^ G) * 8)]);
      }
#pragma unroll
      for (int m = 0; m < 2; ++m)
#pragma unroll
        for (int j = 0; j < 4; ++j) acc[m][j] = MFMA16(a[m], bb[j], acc[m][j]);
    }
  }
  size_t base = (size_t)blk * HD * SSZ;
#pragma unroll
  for (int m = 0; m < 2; ++m)
#pragma unroll
    for (int j = 0; j < 4; ++j)
#pragma unroll
      for (int r = 0; r < 4; ++r) {
        int p = wm * 32 + m * 16 + hi * 4 + r;
        int n = wn * 64 + j * 16 + sl;
        cs[base + (size_t)p * SSZ + n] = acc[m][j][r];
      }
}

// ---------------- inter-chunk recurrence (in-place) ----------------
__global__ __launch_bounds__(256) void chunk_rec_k(const float* __restrict__ acum,
                                                   float* __restrict__ cs) {
  int idx = blockIdx.x * 256 + threadIdx.x;
  int n = idx & 127;
  int p = (idx >> 7) & 63;
  int h = (idx >> 13) & 63;
  int b = idx >> 19;
  float run = 0.f;
#pragma unroll
  for (int c = 0; c < NC; c++) {
    size_t off = ((size_t)(((b * NC + c) * NH + h) * HD + p)) * SSZ + n;
    float csv = cs[off];
    float al = acum[((size_t)((b * NH + h) * NC + c)) * CHK + (CHK - 1)];
    cs[off] = run;
    run = run * __expf(al) + csv;
  }
}

// ================= chunk output via MFMA (flash-style) =======================
__global__ __launch_bounds__(256) void chunk_out_mfma(const bf16* __restrict__ convo,
                                                      const float* __restrict__ dtp,
                                                      const float* __restrict__ acum,
                                                      const float* __restrict__ cs,
                                                      const float* __restrict__ Dp,
                                                      bf16* __restrict__ yb) {
  __shared__ float sAc[CHK];
  __shared__ float sDt[CHK];
  __shared__ __align__(16) unsigned short sB[64 * 128];
  __shared__ __align__(16) unsigned short sH[64 * 64];
  __shared__ __align__(16) unsigned short sW[4 * 64 * 64];
  const int tid = threadIdx.x;
  const int lane = tid & 63, hi = lane >> 4, sl = lane & 15;
  const int wid = tid >> 6;
  const int blk = blockIdx.x;
  const int h = blk & 63;
  const int bc = blk >> 6;
  const int c = bc & 7;
  const int b = bc >> 3;
  const int g = h >> 3;
  const int row0 = b * S_LEN + c * CHK;
  unsigned short* sWp = &sW[wid * 4096];

  sAc[tid] = acum[((size_t)((b * NH + h) * NC + c)) * CHK + tid];
  sDt[tid] = dtp[(size_t)(row0 + tid) * NH + h];

  bf16x8 cf[4][4];
#pragma unroll
  for (int m = 0; m < 4; ++m)
#pragma unroll
    for (int kc = 0; kc < 4; ++kc) {
      int l = wid * 64 + m * 16 + sl;
      U16x8 u;
      u.u = *reinterpret_cast<const uint4*>(
          &convo[(size_t)(row0 + l) * CONV_DIM + C_OFF + g * SSZ + kc * 32 + hi * 8]);
      cf[m][kc] = u.v;
    }

  f32x4 acc[4][4] = {};

  for (int st = 0; st < 4; ++st) {
    __syncthreads();
#pragma unroll
    for (int it = 0; it < 4; ++it) {
      int cid = tid + it * 256;
      int s = cid >> 4, gr = cid & 15;
      const uint4* p = reinterpret_cast<const uint4*>(
          &convo[(size_t)(row0 + st * 64 + s) * CONV_DIM + B_OFF + g * SSZ + gr * 8]);
      *reinterpret_cast<uint4*>(&sB[s * 128 + (gr ^ (s & 7)) * 8]) = *p;
    }
#pragma unroll
    for (int it = 0; it < 16; ++it) {
      int cid = tid + it * 256;
      int s = cid >> 6, pp = cid & 63;
      float v = ldf(&convo[(size_t)(row0 + st * 64 + s) * CONV_DIM + h * HD + pp]) *
                sDt[st * 64 + s];
      sH[pp * 64 + (((s >> 3) ^ (pp & 7)) * 8) + (s & 7)] = f2bu(v);
    }
    __syncthreads();
    if (wid >= st) {
#pragma unroll
      for (int sf = 0; sf < 4; ++sf) {
        f32x4 d[4] = {};
#pragma unroll
        for (int kc = 0; kc < 4; ++kc) {
          int srow = sf * 16 + sl;
          bf16x8 bfv = *reinterpret_cast<const bf16x8*>(
              &sB[srow * 128 + (((kc * 4 + hi) ^ (srow & 7)) * 8)]);
#pragma unroll
          for (int m = 0; m < 4; ++m) d[m] = MFMA16(cf[m][kc], bfv, d[m]);
        }
        int s_loc = sf * 16 + sl;
        int s_glob = st * 64 + s_loc;
        float acS = sAc[s_glob];
        bool diag = (st == wid);
#pragma unroll
        for (int m = 0; m < 4; ++m)
#pragma unroll
          for (int r = 0; r < 4; ++r) {
            int l_loc = m * 16 + hi * 4 + r;
            int l_glob = wid * 64 + l_loc;
            float e = __expf(sAc[l_glob] - acS);
            float v = d[m][r] * e;
            if (diag && s_glob > l_glob) v = 0.f;
            sWp[l_loc * 64 + (((s_loc >> 3) ^ (l_loc & 7)) * 8) + (s_loc & 7)] = f2bu(v);
          }
      }
    }
    __syncthreads();
    if (wid >= st) {
#pragma unroll
      for (int kc = 0; kc < 2; ++kc) {
        bf16x8 a[4], bb[4];
#pragma unroll
        for (int m = 0; m < 4; ++m) {
          int l = m * 16 + sl;
          a[m] = *reinterpret_cast<const bf16x8*>(
              &sWp[l * 64 + (((kc * 4 + hi) ^ (l & 7)) * 8)]);
        }
#pragma unroll
        for (int j = 0; j < 4; ++j) {
          int p = j * 16 + sl;
          bb[j] = *reinterpret_cast<const bf16x8*>(
              &sH[p * 64 + (((kc * 4 + hi) ^ (p & 7)) * 8)]);
        }
#pragma unroll
        for (int m = 0; m < 4; ++m)
#pragma unroll
          for (int j = 0; j < 4; ++j) acc[m][j] = MFMA16(a[m], bb[j], acc[m][j]);
      }
    }
  }

  __syncthreads();
  {
    size_t sinbase = ((size_t)(((b * NC + c) * NH + h) * HD)) * SSZ;
#pragma unroll
    for (int it = 0; it < 8; ++it) {
      int cid = tid + it * 256;
      int p = cid >> 5, q = cid & 31;
      float4 v = *reinterpret_cast<const float4*>(&cs[sinbase + (size_t)p * SSZ + q * 4]);
      uint2 val = make_uint2(pack2(v.x, v.y), pack2(v.z, v.w));
      *reinterpret_cast<uint2*>(&sB[p * 128 + ((q >> 1) ^ (p & 7)) * 8 + (q & 1) * 4]) = val;
    }
  }
  __syncthreads();
#pragma unroll
  for (int m = 0; m < 4; ++m) {
    float e = __expf(sAc[wid * 64 + m * 16 + sl]);
#pragma unroll
    for (int kc = 0; kc < 4; ++kc) {
      bf16x8 fv = cf[m][kc];
#pragma unroll
      for (int ei = 0; ei < 8; ++ei) {
        unsigned short us = (unsigned short)fv[ei];
        fv[ei] = (short)f2bu(bu2f(us) * e);
      }
      cf[m][kc] = fv;
    }
  }
#pragma unroll
  for (int kc = 0; kc < 4; ++kc) {
    bf16x8 bb[4];
#pragma unroll
    for (int j = 0; j < 4; ++j) {
      int p = j * 16 + sl;
      bb[j] = *reinterpret_cast<const bf16x8*>(
          &sB[p * 128 + (((kc * 4 + hi) ^ (p & 7)) * 8)]);
    }
#pragma unroll
    for (int m = 0; m < 4; ++m)
#pragma unroll
      for (int j = 0; j < 4; ++j) acc[m][j] = MFMA16(cf[m][kc], bb[j], acc[m][j]);
  }

  float Dh = Dp[h];
#pragma unroll
  for (int m = 0; m < 4; ++m)
#pragma unroll
    for (int j = 0; j < 4; ++j)
#pragma unroll
      for (int r = 0; r < 4; ++r) {
        int l_glob = wid * 64 + m * 16 + hi * 4 + r;
        size_t row = (size_t)(row0 + l_glob);
        int pg = j * 16 + sl;
        float hraw = ldf(&convo[row * CONV_DIM + h * HD + pg]);
        yb[row * INTER + h * HD + pg] = __float2bfloat16(acc[m][j][r] + Dh * hraw);
      }
}

// ------------- gate SiLU + RMSNorm (in-place on yb), bf16x8 -------------
__global__ __launch_bounds__(256) void norm_k(const bf16* __restrict__ proj,
                                              const float* __restrict__ nw,
                                              bf16* __restrict__ yb) {
  int row = blockIdx.x;
  int tid = threadIdx.x;
  float vals[16];
  float ss = 0.f;
#pragma unroll
  for (int half = 0; half < 2; half++) {
    int colb = tid * 8 + half * 2048;
    U16x8 gy, gg;
    gy.u = *reinterpret_cast<const uint4*>(&yb[(size_t)row * INTER + colb]);
    gg.u = *reinterpret_cast<const uint4*>(&proj[(size_t)row * PROJ_DIM + colb]);
#pragma unroll
    for (int e = 0; e < 8; e++) {
      float yf = bu2f((unsigned short)gy.v[e]) * siluf(bu2f((unsigned short)gg.v[e]));
      vals[half * 8 + e] = yf;
      ss += yf * yf;
    }
  }
#pragma unroll
  for (int off = 32; off > 0; off >>= 1) ss += __shfl_down(ss, off);
  __shared__ float red[4];
  if ((tid & 63) == 0) red[tid >> 6] = ss;
  __syncthreads();
  float tot = red[0] + red[1] + red[2] + red[3];
  float scale = rsqrtf(tot * (1.f / INTER) + 1e-6f);
#pragma unroll
  for (int half = 0; half < 2; half++) {
    int colb = tid * 8 + half * 2048;
    float4 w0 = *reinterpret_cast<const float4*>(&nw[colb]);
    float4 w1 = *reinterpret_cast<const float4*>(&nw[colb + 4]);
    float s0 = vals[half * 8 + 0] * scale * w0.x, s1 = vals[half * 8 + 1] * scale * w0.y;
    float s2 = vals[half * 8 + 2] * scale * w0.z, s3 = vals[half * 8 + 3] * scale * w0.w;
    float s4 = vals[half * 8 + 4] * scale * w1.x, s5 = vals[half * 8 + 5] * scale * w1.y;
    float s6 = vals[half * 8 + 6] * scale * w1.z, s7 = vals[half * 8 + 7] * scale * w1.w;
    uint4 o = make_uint4(pack2(s0, s1), pack2(s2, s3), pack2(s4, s5), pack2(s6, s7));
    *reinterpret_cast<uint4*>(&yb[(size_t)row * INTER + colb]) = o;
  }
}

extern "C" void kernel_launch(void* const* d_in, const int* in_sizes, int n_in,
                              void* d_out, int out_size, void* d_ws, size_t ws_size,
                              hipStream_t stream) {
  const float* x     = (const float*)d_in[0];
  const float* wproj = (const float*)d_in[1];
  const float* cw    = (const float*)d_in[2];
  const float* cb    = (const float*)d_in[3];
  const float* dtb   = (const float*)d_in[4];
  const float* alog  = (const float*)d_in[5];
  const float* Dp    = (const float*)d_in[6];
  const float* nw    = (const float*)d_in[7];
  const float* wout  = (const float*)d_in[8];
  float* out = (float*)d_out;
  char* ws = (char*)d_ws;

  // persistent layout (~195 MiB, proven safe)
  bf16*  proj  = (bf16*)(ws);                    // 84,410,368 B
  bf16*  convo = (bf16*)(ws + 84410368);         // 50,331,648 B
  bf16*  yb    = (bf16*)(ws + 134742016);        // 33,554,432 B
  float* dtp   = (float*)(ws + 168296448);       //  1,048,576 B
  float* acum  = (float*)(ws + 169345024);       //  1,048,576 B
  float* cs    = (float*)(ws + 170393600);       // 33,554,432 B
  // liveness-overlapped temporaries:
  unsigned short* Wt1 = (unsigned short*)(ws + 84410368);   // in convo (43.0MB < 50.3MB)
  unsigned short* xb  = (unsigned short*)(ws + 134742016);  // in yb
  unsigned short* Wt2 = (unsigned short*)(ws + 170393600);  // in cs (dead after chunk_out)
  float* part = (float*)(ws);   // split-K partials in proj region (67MB < 84MB; proj dead after norm_k)

  hipFuncSetAttribute(reinterpret_cast<const void*>(&gemm_8ph<bf16>),
                      hipFuncAttributeMaxDynamicSharedMemorySize, 147456);
  hipFuncSetAttribute(reinterpret_cast<const void*>(&gemm_8ph<float>),
                      hipFuncAttributeMaxDynamicSharedMemorySize, 147456);

  cvt_bf16_k<<<dim3(2048), 256, 0, stream>>>(x, xb, ROWS * HIDDEN / 4);
  wT_k<<<dim3(PROJ_PAD / 64, HIDDEN / 64), 256, 0, stream>>>(wproj, Wt1, HIDDEN, PROJ_DIM);
  gemm_8ph<bf16><<<dim3(PROJ_PAD / 256, ROWS / 256, 1), 512, 147456, stream>>>(
      xb, Wt1, proj, ROWS, PROJ_DIM, HIDDEN, HIDDEN);
  conv_silu_k<<<dim3(ROWS * CONV_DIM / 8 / 256), 256, 0, stream>>>(proj, cw, cb, convo);
  dt_k<<<dim3(ROWS * NH / 256), 256, 0, stream>>>(proj, dtb, dtp);
  acum_k<<<dim3(2 * NH * NC), 256, 0, stream>>>(dtp, alog, acum);
  chunk_states_mfma<<<dim3(2 * NC * NH), 256, 0, stream>>>(convo, dtp, acum, cs);
  chunk_rec_k<<<dim3(2 * NH * HD * SSZ / 256), 256, 0, stream>>>(acum, cs);
  chunk_out_mfma<<<dim3(2 * NC * NH), 256, 0, stream>>>(convo, dtp, acum, cs, Dp, yb);
  norm_k<<<dim3(ROWS), 256, 0, stream>>>(proj, nw, yb);
  wT_k<<<dim3(HIDDEN / 64, INTER / 64), 256, 0, stream>>>(wout, Wt2, INTER, HIDDEN);
  // out-proj: split-K=2 over 256 blocks (1/CU), fp32 partials, then reduce
  gemm_8ph<float><<<dim3(HIDDEN / 256, ROWS / 256, 2), 512, 147456, stream>>>(
      (const unsigned short*)yb, Wt2, part, ROWS, HIDDEN, INTER, INTER / 2);
  add_k<<<dim3(2048), 256, 0, stream>>>(part, part + (size_t)ROWS * HIDDEN, out,
                                        ROWS * HIDDEN / 4);
}